// Round 2
// baseline (6780.517 us; speedup 1.0000x reference)
//
#include <hip/hip_runtime.h>
#include <hip/hip_bf16.h>

typedef __hip_bfloat16 bf16;

#define TOK    1024
#define DIM    96
#define HIDN   384
#define HEADS  8
#define DH     768
#define INNER  6144
#define SEQ    512
#define NDEPTH 5
#define EPSLN  1e-5f
#define QSCALE 0.125f

__device__ __forceinline__ float b2f(bf16 v) { return __bfloat162float(v); }
__device__ __forceinline__ bf16  f2b(float v) { return __float2bfloat16(v); }

// Load element i from an external input buffer whose dtype is decided at
// runtime: f==1 -> bf16, f==0 -> fp32.
__device__ __forceinline__ float gload(const void* p, size_t i, int f) {
  return f ? b2f(((const bf16*)p)[i]) : ((const float*)p)[i];
}

// ---------------- dtype detector ----------------
// Scans the first 1024 EVEN halfwords of x. If the buffer is bf16, every
// halfword is a real bf16 of N(0,1) data -> exponent in [87,132] (~always).
// If the buffer is fp32, even halfwords are low mantissa bits -> exponent
// ~uniform -> ~18% pass. Writes flag=1 (bf16) or 0 (fp32).
__global__ __launch_bounds__(256) void detect_kernel(const void* xraw, int* flag) {
  __shared__ int cnt[256];
  int t = threadIdx.x;
  const unsigned short* u = (const unsigned short*)xraw;
  int c = 0;
  #pragma unroll
  for (int i = 0; i < 4; i++) {
    int idx = 2 * (t * 4 + i);        // 0..2046, within 4 KB — safe either dtype
    unsigned short h = u[idx];
    int e = (h >> 7) & 0xFF;
    if (e >= 87 && e <= 132) c++;
  }
  cnt[t] = c;
  __syncthreads();
  for (int s = 128; s > 0; s >>= 1) {
    if (t < s) cnt[t] += cnt[t + s];
    __syncthreads();
  }
  if (t == 0) *flag = (cnt[0] > 700) ? 1 : 0;
}

// ---------------- cast input x -> fp32 ----------------
__global__ __launch_bounds__(256) void cast_kernel(const void* __restrict__ in,
                                                   float* __restrict__ out, int n,
                                                   const int* __restrict__ flagp) {
  int f = *flagp;
  int i = blockIdx.x * blockDim.x + threadIdx.x;
  if (i < n) out[i] = gload(in, i, f);
}

// ---------------- LayerNorm over rows of length 96 ----------------
// out = (x - mu) * rsqrt(var + eps) * (g + 1).
// outb: bf16 internally; if extout and input dtype is fp32, writes fp32.
__global__ __launch_bounds__(256) void ln_kernel(
    const float* __restrict__ X, const void* __restrict__ gbase, size_t goff,
    void* __restrict__ outb, float* __restrict__ outf, int rows, int extout,
    const int* __restrict__ flagp) {
  int f = *flagp;
  const char* g = (const char*)gbase + goff * (size_t)(f ? 2 : 4);
  int row  = blockIdx.x * 4 + (threadIdx.x >> 6);
  int lane = threadIdx.x & 63;
  if (row >= rows) return;
  const float* xr = X + (size_t)row * DIM;
  float v0 = xr[lane];
  float v1 = (lane < 32) ? xr[64 + lane] : 0.f;
  float s = v0 + v1;
  #pragma unroll
  for (int off = 32; off > 0; off >>= 1) s += __shfl_xor(s, off);
  float mu = s * (1.f / 96.f);
  float d0 = v0 - mu;
  float d1 = (lane < 32) ? (v1 - mu) : 0.f;
  float q = d0 * d0 + d1 * d1;
  #pragma unroll
  for (int off = 32; off > 0; off >>= 1) q += __shfl_xor(q, off);
  float rstd = rsqrtf(q * (1.f / 96.f) + EPSLN);
  bool w32 = (extout && !f);
  float g0 = gload(g, lane, f) + 1.f;
  float o0 = d0 * rstd * g0;
  size_t base = (size_t)row * DIM;
  if (outb) {
    if (w32) ((float*)outb)[base + lane] = o0;
    else     ((bf16*)outb)[base + lane] = f2b(o0);
  }
  if (outf) outf[base + lane] = o0;
  if (lane < 32) {
    float g1 = gload(g, 64 + lane, f) + 1.f;
    float o1 = d1 * rstd * g1;
    if (outb) {
      if (w32) ((float*)outb)[base + 64 + lane] = o1;
      else     ((bf16*)outb)[base + 64 + lane] = f2b(o1);
    }
    if (outf) outf[base + 64 + lane] = o1;
  }
}

// ---------------- softmax over rows of length 512 ----------------
// Reads f32 row from S, writes bf16 IN PLACE over the first half of the same
// row's storage (P row stride = 1024 bf16 elements = sim row stride).
__global__ __launch_bounds__(256) void softmax_kernel(float* __restrict__ S) {
  int row  = blockIdx.x * 4 + (threadIdx.x >> 6);
  int lane = threadIdx.x & 63;
  float* sr = S + (size_t)row * SEQ;
  float v[8];
  float mx = -1e30f;
  #pragma unroll
  for (int i = 0; i < 8; i++) { v[i] = sr[lane + 64 * i]; mx = fmaxf(mx, v[i]); }
  #pragma unroll
  for (int off = 32; off > 0; off >>= 1) mx = fmaxf(mx, __shfl_xor(mx, off));
  float sum = 0.f;
  #pragma unroll
  for (int i = 0; i < 8; i++) { v[i] = expf(v[i] - mx); sum += v[i]; }
  #pragma unroll
  for (int off = 32; off > 0; off >>= 1) sum += __shfl_xor(sum, off);
  float inv = 1.f / sum;
  bf16* pr = (bf16*)sr;                      // in-place: first 1024B of this row
  #pragma unroll
  for (int i = 0; i < 8; i++) pr[lane + 64 * i] = f2b(v[i] * inv);
}

// ---------------- generic 64x64 tile GEMM body (fp32 vector FMA) ------------
// BT=false: C += A[M,K] * B[K,N]; BT=true: C += A[M,K] * B^T (B is [N,K]).
// A is always internal bf16; B dtype selected by fB (1=bf16, 0=f32).
template <bool BT>
__device__ __forceinline__ void gemm_tile(
    const bf16* __restrict__ A, int lda,
    const void* __restrict__ B, int ldb, int fB,
    int m0, int n0, int kbeg, int kend, int M, int N,
    float (*As)[68], float (*Bs)[68], float acc[4][4]) {
  int t = threadIdx.x;
  int tx = t & 15, ty = t >> 4;
  for (int kb = kbeg; kb < kend; kb += 16) {
    #pragma unroll
    for (int i = 0; i < 4; i++) {
      int idx = t + i * 256;
      int r = idx >> 4, c = idx & 15;   // r = m-in-tile, c = k-in-chunk
      int gm = m0 + r;
      float val = 0.f;
      if (gm < M) val = b2f(A[(size_t)gm * lda + (kb + c)]);
      As[c][r] = val;
    }
    #pragma unroll
    for (int i = 0; i < 4; i++) {
      int idx = t + i * 256;
      if (BT) {
        int r = idx >> 4, c = idx & 15;  // r = n-in-tile, c = k-in-chunk
        int gn = n0 + r;
        float val = 0.f;
        if (gn < N) val = gload(B, (size_t)gn * ldb + (kb + c), fB);
        Bs[c][r] = val;
      } else {
        int r = idx >> 6, c = idx & 63;  // r = k-in-chunk, c = n-in-tile
        int gn = n0 + c;
        float val = 0.f;
        if (gn < N) val = gload(B, (size_t)(kb + r) * ldb + gn, fB);
        Bs[r][c] = val;
      }
    }
    __syncthreads();
    #pragma unroll
    for (int kk = 0; kk < 16; kk++) {
      float4 a4 = *reinterpret_cast<const float4*>(&As[kk][ty * 4]);
      float4 b4 = *reinterpret_cast<const float4*>(&Bs[kk][tx * 4]);
      float av[4] = {a4.x, a4.y, a4.z, a4.w};
      float bv[4] = {b4.x, b4.y, b4.z, b4.w};
      #pragma unroll
      for (int i = 0; i < 4; i++)
        #pragma unroll
        for (int j = 0; j < 4; j++)
          acc[i][j] += av[i] * bv[j];
    }
    __syncthreads();
  }
}

// ---------------- NN GEMM, external weights B (dtype via flag) --------------
// grid: (ceil(N/64), ceil(M/64), kSplit); Kc = K chunk per z.
// accum=1: atomicAdd into Cf. bias added by z==0 only.
__global__ __launch_bounds__(256) void gemm_nn_kernel(
    const bf16* __restrict__ A, int lda,
    const void* __restrict__ Bbase, size_t Boff, int ldb,
    const void* __restrict__ biasBase, size_t biasOff,
    bf16* __restrict__ Cb, float* __restrict__ Cf, int ldc,
    int M, int N, int K, int Kc, float alpha, int doGelu, int accum,
    const int* __restrict__ flagp) {
  __shared__ __align__(16) float As[16][68];
  __shared__ __align__(16) float Bs[16][68];
  int f = *flagp;
  size_t esz = f ? 2 : 4;
  const void* B = (const char*)Bbase + Boff * esz;
  const void* bias = biasBase ? (const void*)((const char*)biasBase + biasOff * esz) : nullptr;
  int m0 = blockIdx.y * 64, n0 = blockIdx.x * 64;
  int kbeg = blockIdx.z * Kc;
  int kend = min(K, kbeg + Kc);
  float acc[4][4] = {};
  gemm_tile<false>(A, lda, B, ldb, f, m0, n0, kbeg, kend, M, N, As, Bs, acc);
  int tx = threadIdx.x & 15, ty = threadIdx.x >> 4;
  #pragma unroll
  for (int i = 0; i < 4; i++) {
    int m = m0 + ty * 4 + i;
    if (m >= M) continue;
    #pragma unroll
    for (int j = 0; j < 4; j++) {
      int n = n0 + tx * 4 + j;
      if (n >= N) continue;
      float v = acc[i][j] * alpha;
      if (bias && blockIdx.z == 0) v += gload(bias, n, f);
      if (doGelu) v = 0.5f * v * (1.f + erff(v * 0.70710678118f));
      size_t cidx = (size_t)m * ldc + n;
      if (accum) atomicAdd(Cf + cidx, v);
      else Cb[cidx] = f2b(v);
    }
  }
}

// ---------------- sim = q @ k^T per (b,h), f32 out --------------------------
__global__ __launch_bounds__(256) void sim_kernel(
    const bf16* __restrict__ q, const bf16* __restrict__ k, float* __restrict__ sim) {
  __shared__ __align__(16) float As[16][68];
  __shared__ __align__(16) float Bs[16][68];
  int z = blockIdx.z;
  size_t hoff = (size_t)(z >> 3) * SEQ * INNER + (size_t)(z & 7) * DH;
  const bf16* Az = q + hoff;
  const bf16* Bz = k + hoff;
  float* Cz = sim + (size_t)z * SEQ * SEQ;
  int m0 = blockIdx.y * 64, n0 = blockIdx.x * 64;
  float acc[4][4] = {};
  gemm_tile<true>(Az, INNER, (const void*)Bz, INNER, 1, m0, n0, 0, DH, SEQ, SEQ, As, Bs, acc);
  int tx = threadIdx.x & 15, ty = threadIdx.x >> 4;
  #pragma unroll
  for (int i = 0; i < 4; i++) {
    int m = m0 + ty * 4 + i;
    #pragma unroll
    for (int j = 0; j < 4; j++) {
      int n = n0 + tx * 4 + j;
      Cz[(size_t)m * SEQ + n] = acc[i][j];
    }
  }
}

// ---------------- o = P @ v per (b,h), bf16 out -----------------------------
// P rows have stride 1024 bf16 elements (in-place over sim's f32 rows).
__global__ __launch_bounds__(256) void av_kernel(
    const bf16* __restrict__ P, const bf16* __restrict__ v, bf16* __restrict__ o) {
  __shared__ __align__(16) float As[16][68];
  __shared__ __align__(16) float Bs[16][68];
  int z = blockIdx.z;
  const bf16* Az = P + (size_t)z * SEQ * 1024;
  size_t hoff = (size_t)(z >> 3) * SEQ * INNER + (size_t)(z & 7) * DH;
  const bf16* Bz = v + hoff;
  bf16* Cz = o + hoff;
  int m0 = blockIdx.y * 64, n0 = blockIdx.x * 64;
  float acc[4][4] = {};
  gemm_tile<false>(Az, 1024, (const void*)Bz, INNER, 1, m0, n0, 0, SEQ, SEQ, DH, As, Bs, acc);
  int tx = threadIdx.x & 15, ty = threadIdx.x >> 4;
  #pragma unroll
  for (int i = 0; i < 4; i++) {
    int m = m0 + ty * 4 + i;
    #pragma unroll
    for (int j = 0; j < 4; j++) {
      int n = n0 + tx * 4 + j;
      Cz[(size_t)m * INNER + n] = f2b(acc[i][j]);
    }
  }
}

// ---------------- host-side orchestration ----------------
extern "C" void kernel_launch(void* const* d_in, const int* in_sizes, int n_in,
                              void* d_out, int out_size, void* d_ws, size_t ws_size,
                              hipStream_t stream) {
  const void* in_x    = d_in[0];
  const void* gam_a   = d_in[1];
  const void* Wq      = d_in[2];
  const void* Wk      = d_in[3];
  const void* Wv      = d_in[4];
  const void* Wo      = d_in[5];
  const void* gam_m   = d_in[6];
  const void* W1      = d_in[7];
  const void* b1      = d_in[8];
  const void* W2      = d_in[9];
  const void* b2      = d_in[10];
  const void* gam_mid = d_in[11];
  const void* gam_fin = d_in[12];

  char* wsb = (char*)d_ws;
  size_t off = 0;
  auto carve = [&](size_t bytes) {
    char* p = wsb + off;
    off += (bytes + 255) & ~(size_t)255;
    return p;
  };
  int*   flag = (int*)carve(256);
  float* x    = (float*)carve((size_t)TOK * DIM * 4);
  bf16*  h    = (bf16*)carve((size_t)TOK * DIM * 2);
  bf16*  q    = (bf16*)carve((size_t)TOK * INNER * 2);   // reused as o
  bf16*  k    = (bf16*)carve((size_t)TOK * INNER * 2);
  bf16*  v    = (bf16*)carve((size_t)TOK * INNER * 2);
  float* sim  = (float*)carve((size_t)16 * SEQ * SEQ * 4); // P lives in-place
  bf16*  hid  = (bf16*)carve((size_t)TOK * HIDN * 2);
  bf16*  o    = q;
  bf16*  P    = (bf16*)sim;

  detect_kernel<<<dim3(1), dim3(256), 0, stream>>>(in_x, flag);
  cast_kernel<<<dim3((TOK * DIM + 255) / 256), dim3(256), 0, stream>>>(in_x, x, TOK * DIM, flag);

  auto attn = [&](int d, int j) {
    size_t gi = ((size_t)d * 3 + j);
    ln_kernel<<<dim3(TOK / 4), dim3(256), 0, stream>>>(x, gam_a, gi * DIM, h, nullptr, TOK, 0, flag);
    // q/k/v projections: M=1024, N=6144, K=96
    gemm_nn_kernel<<<dim3(96, 16, 1), dim3(256), 0, stream>>>(
        h, DIM, Wq, gi * (size_t)DIM * INNER, INNER, nullptr, 0,
        q, nullptr, INNER, TOK, INNER, DIM, DIM, QSCALE, 0, 0, flag);
    gemm_nn_kernel<<<dim3(96, 16, 1), dim3(256), 0, stream>>>(
        h, DIM, Wk, gi * (size_t)DIM * INNER, INNER, nullptr, 0,
        k, nullptr, INNER, TOK, INNER, DIM, DIM, 1.f, 0, 0, flag);
    gemm_nn_kernel<<<dim3(96, 16, 1), dim3(256), 0, stream>>>(
        h, DIM, Wv, gi * (size_t)DIM * INNER, INNER, nullptr, 0,
        v, nullptr, INNER, TOK, INNER, DIM, DIM, 1.f, 0, 0, flag);
    sim_kernel<<<dim3(8, 8, 16), dim3(256), 0, stream>>>(q, k, sim);
    softmax_kernel<<<dim3(16 * SEQ / 4), dim3(256), 0, stream>>>(sim);
    av_kernel<<<dim3(12, 8, 16), dim3(256), 0, stream>>>(P, v, o);
    // x += o @ Wo : M=1024, N=96, K=6144, split-K 32 x 192
    gemm_nn_kernel<<<dim3(2, 16, 32), dim3(256), 0, stream>>>(
        o, INNER, Wo, gi * (size_t)INNER * DIM, DIM, nullptr, 0,
        nullptr, x, DIM, TOK, DIM, INNER, 192, 1.f, 0, 1, flag);
  };

  auto mlp = [&](int d, int i) {
    size_t gi = ((size_t)d * 2 + i);
    ln_kernel<<<dim3(TOK / 4), dim3(256), 0, stream>>>(x, gam_m, gi * DIM, h, nullptr, TOK, 0, flag);
    // hid = gelu(h @ W1 + b1): M=1024, N=384, K=96
    gemm_nn_kernel<<<dim3(6, 16, 1), dim3(256), 0, stream>>>(
        h, DIM, W1, gi * (size_t)DIM * HIDN, HIDN, b1, gi * HIDN,
        hid, nullptr, HIDN, TOK, HIDN, DIM, DIM, 1.f, 1, 0, flag);
    // x += hid @ W2 + b2: M=1024, N=96, K=384, split-K 8 x 48
    gemm_nn_kernel<<<dim3(2, 16, 8), dim3(256), 0, stream>>>(
        hid, HIDN, W2, gi * (size_t)HIDN * DIM, DIM, b2, gi * DIM,
        nullptr, x, DIM, TOK, DIM, HIDN, 48, 1.f, 0, 1, flag);
  };

  for (int d = 0; d < NDEPTH; d++) {
    attn(d, 0);
    mlp(d, 0);
    attn(d, 1);
    attn(d, 2);
    ln_kernel<<<dim3(TOK / 4), dim3(256), 0, stream>>>(x, gam_mid, (size_t)d * DIM, nullptr, x, TOK, 0, flag);
    mlp(d, 1);
  }
  ln_kernel<<<dim3(TOK / 4), dim3(256), 0, stream>>>(x, gam_fin, 0, d_out, nullptr, TOK, 1, flag);
}

// Round 3
// 2548.125 us; speedup vs baseline: 2.6610x; 2.6610x over previous
//
#include <hip/hip_runtime.h>
#include <hip/hip_bf16.h>

typedef __hip_bfloat16 bf16;
typedef __attribute__((ext_vector_type(8))) short bf16x8;   // 8 bf16 = 4 VGPRs
typedef __attribute__((ext_vector_type(4))) float f32x4;

#define TOK    1024
#define DIM    96
#define HIDN   384
#define HEADS  8
#define DH     768
#define INNER  6144
#define SEQ    512
#define NDEPTH 5
#define EPSLN  1e-5f
#define QSCALE 0.125f

__device__ __forceinline__ float b2f(bf16 v) { return __bfloat162float(v); }
__device__ __forceinline__ bf16  f2b(float v) { return __float2bfloat16(v); }

// Load element i from an external input buffer: f==1 -> bf16, f==0 -> fp32.
__device__ __forceinline__ float gload(const void* p, size_t i, int f) {
  return f ? b2f(((const bf16*)p)[i]) : ((const float*)p)[i];
}

// ---------------- dtype detector (bf16 vs fp32 external buffers) ------------
__global__ __launch_bounds__(256) void detect_kernel(const void* xraw, int* flag) {
  __shared__ int cnt[256];
  int t = threadIdx.x;
  const unsigned short* u = (const unsigned short*)xraw;
  int c = 0;
  #pragma unroll
  for (int i = 0; i < 4; i++) {
    unsigned short h = u[2 * (t * 4 + i)];
    int e = (h >> 7) & 0xFF;
    if (e >= 87 && e <= 132) c++;
  }
  cnt[t] = c;
  __syncthreads();
  for (int s = 128; s > 0; s >>= 1) {
    if (t < s) cnt[t] += cnt[t + s];
    __syncthreads();
  }
  if (t == 0) *flag = (cnt[0] > 700) ? 1 : 0;
}

// ---------------- cast input x -> fp32 ----------------
__global__ __launch_bounds__(256) void cast_kernel(const void* __restrict__ in,
                                                   float* __restrict__ out, int n,
                                                   const int* __restrict__ flagp) {
  int f = *flagp;
  int i = blockIdx.x * blockDim.x + threadIdx.x;
  if (i < n) out[i] = gload(in, i, f);
}

// ---------------- LayerNorm over rows of length 96 ----------------
__global__ __launch_bounds__(256) void ln_kernel(
    const float* __restrict__ X, const void* __restrict__ gbase, size_t goff,
    void* __restrict__ outb, float* __restrict__ outf, int rows, int extout,
    const int* __restrict__ flagp) {
  int f = *flagp;
  const char* g = (const char*)gbase + goff * (size_t)(f ? 2 : 4);
  int row  = blockIdx.x * 4 + (threadIdx.x >> 6);
  int lane = threadIdx.x & 63;
  if (row >= rows) return;
  const float* xr = X + (size_t)row * DIM;
  float v0 = xr[lane];
  float v1 = (lane < 32) ? xr[64 + lane] : 0.f;
  float s = v0 + v1;
  #pragma unroll
  for (int off = 32; off > 0; off >>= 1) s += __shfl_xor(s, off);
  float mu = s * (1.f / 96.f);
  float d0 = v0 - mu;
  float d1 = (lane < 32) ? (v1 - mu) : 0.f;
  float q = d0 * d0 + d1 * d1;
  #pragma unroll
  for (int off = 32; off > 0; off >>= 1) q += __shfl_xor(q, off);
  float rstd = rsqrtf(q * (1.f / 96.f) + EPSLN);
  bool w32 = (extout && !f);
  float g0 = gload(g, lane, f) + 1.f;
  float o0 = d0 * rstd * g0;
  size_t base = (size_t)row * DIM;
  if (outb) {
    if (w32) ((float*)outb)[base + lane] = o0;
    else     ((bf16*)outb)[base + lane] = f2b(o0);
  }
  if (outf) outf[base + lane] = o0;
  if (lane < 32) {
    float g1 = gload(g, 64 + lane, f) + 1.f;
    float o1 = d1 * rstd * g1;
    if (outb) {
      if (w32) ((float*)outb)[base + 64 + lane] = o1;
      else     ((bf16*)outb)[base + 64 + lane] = f2b(o1);
    }
    if (outf) outf[base + 64 + lane] = o1;
  }
}

// ---------------- softmax rows of 512: f32 in, bf16 IN PLACE ----------------
__global__ __launch_bounds__(256) void softmax_kernel(float* __restrict__ S) {
  int row  = blockIdx.x * 4 + (threadIdx.x >> 6);
  int lane = threadIdx.x & 63;
  float* sr = S + (size_t)row * SEQ;
  float v[8];
  float mx = -1e30f;
  #pragma unroll
  for (int i = 0; i < 8; i++) { v[i] = sr[lane + 64 * i]; mx = fmaxf(mx, v[i]); }
  #pragma unroll
  for (int off = 32; off > 0; off >>= 1) mx = fmaxf(mx, __shfl_xor(mx, off));
  float sum = 0.f;
  #pragma unroll
  for (int i = 0; i < 8; i++) { v[i] = expf(v[i] - mx); sum += v[i]; }
  #pragma unroll
  for (int off = 32; off > 0; off >>= 1) sum += __shfl_xor(sum, off);
  float inv = 1.f / sum;
  bf16* pr = (bf16*)sr;
  #pragma unroll
  for (int i = 0; i < 8; i++) pr[lane + 64 * i] = f2b(v[i] * inv);
}

// =================== MFMA GEMM body ===================
// Block = 256 threads = 4 waves (2x2), tile 128x128, wave tile 64x64 (4x4
// mfma_f32_16x16x32_bf16 fragments). M must be a multiple of 128 (true for
// all call sites); N guarded. K span [kbeg,kend) multiple of 32.
// BT=true : B is [N][K] bf16 (row-major, like A) -> direct stage.
// BT=false: B is [K][N] (dtype fB: 1=bf16, 0=f32) -> transpose stage.
// outMode: 0 = bf16 store Cb; 1 = f32 store Cf; 2 = f32 atomicAdd Cf.
template <bool BT>
__device__ __forceinline__ void mfma_gemm_body(
    const bf16* __restrict__ A, int lda,
    const void* __restrict__ B, int ldb, int fB,
    int m0, int n0, int kbeg, int kend, int N,
    float alpha, const void* __restrict__ bias, int fBias, int doGelu,
    bf16* __restrict__ Cb, float* __restrict__ Cf, int outMode, int ldc) {
  __shared__ bf16 As[128][40];   // row stride 80 B (16B-aligned, conflict-light)
  __shared__ bf16 Bs[128][40];   // Bs[n][k]
  int t = threadIdx.x;
  int lane = t & 63;
  int wave = t >> 6;
  int wm = (wave >> 1) * 64, wn = (wave & 1) * 64;
  f32x4 acc[4][4];
  #pragma unroll
  for (int i = 0; i < 4; i++)
    #pragma unroll
    for (int j = 0; j < 4; j++) acc[i][j] = (f32x4){0.f, 0.f, 0.f, 0.f};

  int arow = t >> 2, aseg = (t & 3) * 8;  // A/BT staging: 4 lanes x 8 elems per row
  int kr = t >> 4, nc = (t & 15) * 8;     // transpose staging

  for (int kb = kbeg; kb < kend; kb += 32) {
    // ---- stage A (128 x 32) ----
    *(uint4*)&As[arow][aseg] =
        *(const uint4*)(A + (size_t)(m0 + arow) * lda + kb + aseg);
    *(uint4*)&As[arow + 64][aseg] =
        *(const uint4*)(A + (size_t)(m0 + arow + 64) * lda + kb + aseg);
    // ---- stage B -> Bs[n][k] ----
    if (BT) {
      const bf16* Bb = (const bf16*)B;
      *(uint4*)&Bs[arow][aseg] =
          *(const uint4*)(Bb + (size_t)(n0 + arow) * ldb + kb + aseg);
      *(uint4*)&Bs[arow + 64][aseg] =
          *(const uint4*)(Bb + (size_t)(n0 + arow + 64) * ldb + kb + aseg);
    } else {
      #pragma unroll
      for (int pass = 0; pass < 2; pass++) {
        int kk = kr + pass * 16;
        int gn = n0 + nc;
        bf16 tmp[8];
        if (gn + 8 <= N) {
          if (fB) {
            *(uint4*)tmp =
                *(const uint4*)((const bf16*)B + (size_t)(kb + kk) * ldb + gn);
          } else {
            const float* p = (const float*)B + (size_t)(kb + kk) * ldb + gn;
            float4 r0 = *(const float4*)p;
            float4 r1 = *(const float4*)(p + 4);
            tmp[0] = f2b(r0.x); tmp[1] = f2b(r0.y); tmp[2] = f2b(r0.z); tmp[3] = f2b(r0.w);
            tmp[4] = f2b(r1.x); tmp[5] = f2b(r1.y); tmp[6] = f2b(r1.z); tmp[7] = f2b(r1.w);
          }
        } else {
          #pragma unroll
          for (int j = 0; j < 8; j++) tmp[j] = f2b(0.f);
        }
        #pragma unroll
        for (int j = 0; j < 8; j++) Bs[nc + j][kk] = tmp[j];
      }
    }
    __syncthreads();
    // ---- compute: one K=32 MFMA step per fragment pair ----
    int fm = lane & 15, fq = (lane >> 4) * 8;
    bf16x8 af[4], bfv[4];
    #pragma unroll
    for (int i = 0; i < 4; i++)
      af[i] = *(const bf16x8*)&As[wm + i * 16 + fm][fq];
    #pragma unroll
    for (int j = 0; j < 4; j++)
      bfv[j] = *(const bf16x8*)&Bs[wn + j * 16 + fm][fq];
    #pragma unroll
    for (int i = 0; i < 4; i++)
      #pragma unroll
      for (int j = 0; j < 4; j++)
        acc[i][j] = __builtin_amdgcn_mfma_f32_16x16x32_bf16(af[i], bfv[j], acc[i][j], 0, 0, 0);
    __syncthreads();
  }
  // ---- epilogue: lane holds D[quad*4+r][lane&15] per 16x16 tile ----
  int col = lane & 15, rq = (lane >> 4) * 4;
  #pragma unroll
  for (int j = 0; j < 4; j++) {
    int gn = n0 + wn + j * 16 + col;
    if (gn >= N) continue;
    float bv = bias ? gload(bias, gn, fBias) : 0.f;
    #pragma unroll
    for (int i = 0; i < 4; i++) {
      #pragma unroll
      for (int r = 0; r < 4; r++) {
        int gm = m0 + wm + i * 16 + rq + r;
        float v = acc[i][j][r] * alpha + bv;
        if (doGelu) v = 0.5f * v * (1.f + erff(v * 0.70710678118f));
        size_t cx = (size_t)gm * ldc + gn;
        if (outMode == 0) Cb[cx] = f2b(v);
        else if (outMode == 1) Cf[cx] = v;
        else atomicAdd(Cf + cx, v);
      }
    }
  }
}

// ---- fused QKV projection: grid (48, 8, 3), z selects {q,k,v} --------------
__global__ __launch_bounds__(256) void qkv_kernel(
    const bf16* __restrict__ h,
    const void* __restrict__ Wqb, const void* __restrict__ Wkb,
    const void* __restrict__ Wvb, size_t woff,
    bf16* __restrict__ q, bf16* __restrict__ k, bf16* __restrict__ v,
    const int* __restrict__ flagp) {
  int f = *flagp;
  size_t esz = f ? 2 : 4;
  int z = blockIdx.z;
  const void* W = (z == 0) ? Wqb : (z == 1) ? Wkb : Wvb;
  W = (const char*)W + woff * esz;
  bf16* C = (z == 0) ? q : (z == 1) ? k : v;
  float alpha = (z == 0) ? QSCALE : 1.f;
  mfma_gemm_body<false>(h, DIM, W, INNER, f,
                        blockIdx.y * 128, blockIdx.x * 128, 0, DIM, INNER,
                        alpha, nullptr, 0, 0, C, nullptr, 0, INNER);
}

// ---- sim = q @ k^T per (b,h): grid (4, 4, 16), f32 out ---------------------
__global__ __launch_bounds__(256) void simm_kernel(
    const bf16* __restrict__ q, const bf16* __restrict__ k,
    float* __restrict__ sim) {
  int z = blockIdx.z;
  size_t hoff = (size_t)(z >> 3) * SEQ * INNER + (size_t)(z & 7) * DH;
  mfma_gemm_body<true>(q + hoff, INNER, (const void*)(k + hoff), INNER, 1,
                       blockIdx.y * 128, blockIdx.x * 128, 0, DH, SEQ,
                       1.f, nullptr, 0, 0, nullptr, sim + (size_t)z * SEQ * SEQ, 1, SEQ);
}

// ---- o = P @ v per (b,h): grid (6, 4, 16), P row stride 1024 ---------------
__global__ __launch_bounds__(256) void avm_kernel(
    const bf16* __restrict__ P, const bf16* __restrict__ v,
    bf16* __restrict__ o) {
  int z = blockIdx.z;
  size_t hoff = (size_t)(z >> 3) * SEQ * INNER + (size_t)(z & 7) * DH;
  mfma_gemm_body<false>(P + (size_t)z * SEQ * 1024, 1024,
                        (const void*)(v + hoff), INNER, 1,
                        blockIdx.y * 128, blockIdx.x * 128, 0, SEQ, DH,
                        1.f, nullptr, 0, 0, o + hoff, nullptr, 0, INNER);
}

// ---- generic linear (out-proj / mlp1 / mlp2) with split-K ------------------
__global__ __launch_bounds__(256) void lin_kernel(
    const bf16* __restrict__ A, int lda,
    const void* __restrict__ Bbase, size_t Boff, int ldb,
    const void* __restrict__ biasBase, size_t biasOff,
    bf16* __restrict__ Cb, float* __restrict__ Cf, int outMode, int ldc,
    int N, int K, int Kc, float alpha, int doGelu,
    const int* __restrict__ flagp) {
  int f = *flagp;
  size_t esz = f ? 2 : 4;
  const void* B = (const char*)Bbase + Boff * esz;
  const void* bias = nullptr;
  if (biasBase && blockIdx.z == 0)
    bias = (const void*)((const char*)biasBase + biasOff * esz);
  int kbeg = blockIdx.z * Kc;
  int kend = min(K, kbeg + Kc);
  mfma_gemm_body<false>(A, lda, B, ldb, f,
                        blockIdx.y * 128, blockIdx.x * 128, kbeg, kend, N,
                        alpha, bias, f, doGelu, Cb, Cf, outMode, ldc);
}

// ---------------- host-side orchestration ----------------
extern "C" void kernel_launch(void* const* d_in, const int* in_sizes, int n_in,
                              void* d_out, int out_size, void* d_ws, size_t ws_size,
                              hipStream_t stream) {
  const void* in_x    = d_in[0];
  const void* gam_a   = d_in[1];
  const void* Wq      = d_in[2];
  const void* Wk      = d_in[3];
  const void* Wv      = d_in[4];
  const void* Wo      = d_in[5];
  const void* gam_m   = d_in[6];
  const void* W1      = d_in[7];
  const void* b1      = d_in[8];
  const void* W2      = d_in[9];
  const void* b2      = d_in[10];
  const void* gam_mid = d_in[11];
  const void* gam_fin = d_in[12];

  char* wsb = (char*)d_ws;
  size_t off = 0;
  auto carve = [&](size_t bytes) {
    char* p = wsb + off;
    off += (bytes + 255) & ~(size_t)255;
    return p;
  };
  int*   flag = (int*)carve(256);
  float* x    = (float*)carve((size_t)TOK * DIM * 4);
  bf16*  h    = (bf16*)carve((size_t)TOK * DIM * 2);
  bf16*  q    = (bf16*)carve((size_t)TOK * INNER * 2);   // reused as o
  bf16*  k    = (bf16*)carve((size_t)TOK * INNER * 2);
  bf16*  v    = (bf16*)carve((size_t)TOK * INNER * 2);
  float* sim  = (float*)carve((size_t)16 * SEQ * SEQ * 4); // P lives in-place
  bf16*  hid  = (bf16*)carve((size_t)TOK * HIDN * 2);
  bf16*  o    = q;
  bf16*  P    = (bf16*)sim;

  detect_kernel<<<dim3(1), dim3(256), 0, stream>>>(in_x, flag);
  cast_kernel<<<dim3((TOK * DIM + 255) / 256), dim3(256), 0, stream>>>(in_x, x, TOK * DIM, flag);

  auto attn = [&](int d, int j) {
    size_t gi = ((size_t)d * 3 + j);
    ln_kernel<<<dim3(TOK / 4), dim3(256), 0, stream>>>(x, gam_a, gi * DIM, h, nullptr, TOK, 0, flag);
    qkv_kernel<<<dim3(48, 8, 3), dim3(256), 0, stream>>>(
        h, Wq, Wk, Wv, gi * (size_t)DIM * INNER, q, k, v, flag);
    simm_kernel<<<dim3(4, 4, 16), dim3(256), 0, stream>>>(q, k, sim);
    softmax_kernel<<<dim3(16 * SEQ / 4), dim3(256), 0, stream>>>(sim);
    avm_kernel<<<dim3(6, 4, 16), dim3(256), 0, stream>>>(P, v, o);
    // x += o @ Wo : M=1024, N=96, K=6144, split-K 16 x 384
    lin_kernel<<<dim3(1, 8, 16), dim3(256), 0, stream>>>(
        o, INNER, Wo, gi * (size_t)INNER * DIM, DIM, nullptr, 0,
        nullptr, x, 2, DIM, DIM, INNER, 384, 1.f, 0, flag);
  };

  auto mlp = [&](int d, int i) {
    size_t gi = ((size_t)d * 2 + i);
    ln_kernel<<<dim3(TOK / 4), dim3(256), 0, stream>>>(x, gam_m, gi * DIM, h, nullptr, TOK, 0, flag);
    // hid = gelu(h @ W1 + b1): M=1024, N=384, K=96
    lin_kernel<<<dim3(3, 8, 1), dim3(256), 0, stream>>>(
        h, DIM, W1, gi * (size_t)DIM * HIDN, HIDN, b1, gi * HIDN,
        hid, nullptr, 0, HIDN, HIDN, DIM, DIM, 1.f, 1, flag);
    // x += hid @ W2 + b2: M=1024, N=96, K=384, split-K 4 x 96
    lin_kernel<<<dim3(1, 8, 4), dim3(256), 0, stream>>>(
        hid, HIDN, W2, gi * (size_t)HIDN * DIM, DIM, b2, gi * DIM,
        nullptr, x, 2, DIM, DIM, HIDN, 96, 1.f, 0, flag);
  };

  for (int d = 0; d < NDEPTH; d++) {
    attn(d, 0);
    mlp(d, 0);
    attn(d, 1);
    attn(d, 2);
    ln_kernel<<<dim3(TOK / 4), dim3(256), 0, stream>>>(x, gam_mid, (size_t)d * DIM, nullptr, x, TOK, 0, flag);
    mlp(d, 1);
  }
  ln_kernel<<<dim3(TOK / 4), dim3(256), 0, stream>>>(x, gam_fin, 0, d_out, nullptr, TOK, 1, flag);
}

// Round 4
// 2168.058 us; speedup vs baseline: 3.1275x; 1.1753x over previous
//
#include <hip/hip_runtime.h>
#include <hip/hip_bf16.h>

typedef __hip_bfloat16 bf16;
typedef __attribute__((ext_vector_type(8))) short bf16x8;   // 8 bf16 = 4 VGPRs
typedef __attribute__((ext_vector_type(4))) float f32x4;

#define TOK    1024
#define DIM    96
#define HIDN   384
#define HEADS  8
#define DH     768
#define INNER  6144
#define SEQ    512
#define NDEPTH 5
#define EPSLN  1e-5f
#define QSCALE 0.125f

__device__ __forceinline__ float b2f(bf16 v) { return __bfloat162float(v); }
__device__ __forceinline__ bf16  f2b(float v) { return __float2bfloat16(v); }

// Load element i from an external input buffer: f==1 -> bf16, f==0 -> fp32.
__device__ __forceinline__ float gload(const void* p, size_t i, int f) {
  return f ? b2f(((const bf16*)p)[i]) : ((const float*)p)[i];
}

// ---------------- dtype detector (bf16 vs fp32 external buffers) ------------
__global__ __launch_bounds__(256) void detect_kernel(const void* xraw, int* flag) {
  __shared__ int cnt[256];
  int t = threadIdx.x;
  const unsigned short* u = (const unsigned short*)xraw;
  int c = 0;
  #pragma unroll
  for (int i = 0; i < 4; i++) {
    unsigned short h = u[2 * (t * 4 + i)];
    int e = (h >> 7) & 0xFF;
    if (e >= 87 && e <= 132) c++;
  }
  cnt[t] = c;
  __syncthreads();
  for (int s = 128; s > 0; s >>= 1) {
    if (t < s) cnt[t] += cnt[t + s];
    __syncthreads();
  }
  if (t == 0) *flag = (cnt[0] > 700) ? 1 : 0;
}

// ---------------- cast input x -> fp32 ----------------
__global__ __launch_bounds__(256) void cast_kernel(const void* __restrict__ in,
                                                   float* __restrict__ out, int n,
                                                   const int* __restrict__ flagp) {
  int f = *flagp;
  int i = blockIdx.x * blockDim.x + threadIdx.x;
  if (i < n) out[i] = gload(in, i, f);
}

// ---------------- weight transpose+convert: [bz][R][C] -> bf16 [bz][C][R] ---
// grid (ceil(C/32), ceil(R/32), batches), 256 threads.
__global__ __launch_bounds__(256) void wtrans_kernel(
    const void* __restrict__ src, size_t srcElemOff, int R, int C,
    bf16* __restrict__ dst, const int* __restrict__ flagp) {
  __shared__ float tile[32][33];
  int f = *flagp;
  int t = threadIdx.x;
  int tx = t & 31, ty = t >> 5;           // ty 0..7
  int c0 = blockIdx.x * 32, r0 = blockIdx.y * 32;
  size_t bb = (size_t)blockIdx.z * R * C;
  #pragma unroll
  for (int i = 0; i < 4; i++) {
    int r = r0 + ty + 8 * i, c = c0 + tx;
    float v = 0.f;
    if (r < R && c < C) v = gload(src, srcElemOff + bb + (size_t)r * C + c, f);
    tile[ty + 8 * i][tx] = v;
  }
  __syncthreads();
  #pragma unroll
  for (int i = 0; i < 4; i++) {
    int cc = c0 + ty + 8 * i, rr = r0 + tx;
    if (cc < C && rr < R)
      dst[bb + (size_t)cc * R + rr] = f2b(tile[tx][ty + 8 * i]);
  }
}

// ---------------- v [1024][6144] bf16 -> vT [16][768][512] bf16 -------------
// grid (24, 16, 16): x = d-tile, y = s-tile, z = bh.
__global__ __launch_bounds__(256) void vtrans_kernel(
    const bf16* __restrict__ v, bf16* __restrict__ vT) {
  __shared__ bf16 tile[32][34];
  int t = threadIdx.x;
  int tx = t & 31, ty = t >> 5;
  int z = blockIdx.z, b = z >> 3, h = z & 7;
  int d0 = blockIdx.x * 32, s0 = blockIdx.y * 32;
  #pragma unroll
  for (int i = 0; i < 4; i++) {
    int s = s0 + ty + 8 * i, d = d0 + tx;
    tile[ty + 8 * i][tx] = v[(size_t)(b * 512 + s) * INNER + h * DH + d];
  }
  __syncthreads();
  bf16* out = vT + (size_t)z * DH * SEQ;
  #pragma unroll
  for (int i = 0; i < 4; i++) {
    int d = d0 + ty + 8 * i, s = s0 + tx;
    out[(size_t)d * SEQ + s] = tile[tx][ty + 8 * i];
  }
}

// ---------------- LayerNorm over rows of length 96 ----------------
__global__ __launch_bounds__(256) void ln_kernel(
    const float* __restrict__ X, const void* __restrict__ gbase, size_t goff,
    void* __restrict__ outb, float* __restrict__ outf, int rows, int extout,
    const int* __restrict__ flagp) {
  int f = *flagp;
  const char* g = (const char*)gbase + goff * (size_t)(f ? 2 : 4);
  int row  = blockIdx.x * 4 + (threadIdx.x >> 6);
  int lane = threadIdx.x & 63;
  if (row >= rows) return;
  const float* xr = X + (size_t)row * DIM;
  float v0 = xr[lane];
  float v1 = (lane < 32) ? xr[64 + lane] : 0.f;
  float s = v0 + v1;
  #pragma unroll
  for (int off = 32; off > 0; off >>= 1) s += __shfl_xor(s, off);
  float mu = s * (1.f / 96.f);
  float d0 = v0 - mu;
  float d1 = (lane < 32) ? (v1 - mu) : 0.f;
  float q = d0 * d0 + d1 * d1;
  #pragma unroll
  for (int off = 32; off > 0; off >>= 1) q += __shfl_xor(q, off);
  float rstd = rsqrtf(q * (1.f / 96.f) + EPSLN);
  bool w32 = (extout && !f);
  float g0 = gload(g, lane, f) + 1.f;
  float o0 = d0 * rstd * g0;
  size_t base = (size_t)row * DIM;
  if (outb) {
    if (w32) ((float*)outb)[base + lane] = o0;
    else     ((bf16*)outb)[base + lane] = f2b(o0);
  }
  if (outf) outf[base + lane] = o0;
  if (lane < 32) {
    float g1 = gload(g, 64 + lane, f) + 1.f;
    float o1 = d1 * rstd * g1;
    if (outb) {
      if (w32) ((float*)outb)[base + 64 + lane] = o1;
      else     ((bf16*)outb)[base + 64 + lane] = f2b(o1);
    }
    if (outf) outf[base + 64 + lane] = o1;
  }
}

// ---------------- softmax rows of 512: f32 in, bf16 IN PLACE ----------------
__global__ __launch_bounds__(256) void softmax_kernel(float* __restrict__ S) {
  int row  = blockIdx.x * 4 + (threadIdx.x >> 6);
  int lane = threadIdx.x & 63;
  float* sr = S + (size_t)row * SEQ;
  float v[8];
  float mx = -1e30f;
  #pragma unroll
  for (int i = 0; i < 8; i++) { v[i] = sr[lane + 64 * i]; mx = fmaxf(mx, v[i]); }
  #pragma unroll
  for (int off = 32; off > 0; off >>= 1) mx = fmaxf(mx, __shfl_xor(mx, off));
  float sum = 0.f;
  #pragma unroll
  for (int i = 0; i < 8; i++) { v[i] = expf(v[i] - mx); sum += v[i]; }
  #pragma unroll
  for (int off = 32; off > 0; off >>= 1) sum += __shfl_xor(sum, off);
  float inv = 1.f / sum;
  bf16* pr = (bf16*)sr;
  #pragma unroll
  for (int i = 0; i < 8; i++) pr[lane + 64 * i] = f2b(v[i] * inv);
}

// =================== MFMA GEMM body — BT only (B is bf16 [N][K]) ============
// Block 256 = 4 waves (2x2). WM = wave m-frags (4 -> 128x128 tile, 2 -> 64x128).
// M must be a multiple of the tile (true at all call sites); N guarded.
// mode: 0 = bf16 store Cb; 1 = f32 store Cf; 2 = f32 atomicAdd Cf.
template <int WM>
__device__ __forceinline__ void gemm_bt_body(
    const bf16* __restrict__ A, int lda,
    const bf16* __restrict__ Bt, int ldb,
    int m0, int n0, int kbeg, int kend, int N,
    float alpha, const void* __restrict__ bias, int fbias, int doGelu,
    bf16* __restrict__ Cb, float* __restrict__ Cf, int mode, int ldc) {
  constexpr int TM = WM * 32;
  __shared__ bf16 As[TM][40];
  __shared__ bf16 Bs[128][40];
  int t = threadIdx.x;
  int lane = t & 63;
  int wave = t >> 6;
  int wm = (wave >> 1) * (WM * 16), wn = (wave & 1) * 64;
  f32x4 acc[WM][4];
  #pragma unroll
  for (int i = 0; i < WM; i++)
    #pragma unroll
    for (int j = 0; j < 4; j++) acc[i][j] = (f32x4){0.f, 0.f, 0.f, 0.f};

  int arow = t >> 2, aseg = (t & 3) * 8;

  for (int kb = kbeg; kb < kend; kb += 32) {
    #pragma unroll
    for (int i = 0; i < TM / 64; i++)
      *(uint4*)&As[arow + i * 64][aseg] =
          *(const uint4*)(A + (size_t)(m0 + arow + i * 64) * lda + kb + aseg);
    #pragma unroll
    for (int i = 0; i < 2; i++) {
      int r = arow + i * 64;
      int gn = n0 + r;
      uint4 val = {0, 0, 0, 0};
      if (gn < N) val = *(const uint4*)(Bt + (size_t)gn * ldb + kb + aseg);
      *(uint4*)&Bs[r][aseg] = val;
    }
    __syncthreads();
    int fm = lane & 15, fq = (lane >> 4) * 8;
    bf16x8 af[WM], bfv[4];
    #pragma unroll
    for (int i = 0; i < WM; i++)
      af[i] = *(const bf16x8*)&As[wm + i * 16 + fm][fq];
    #pragma unroll
    for (int j = 0; j < 4; j++)
      bfv[j] = *(const bf16x8*)&Bs[wn + j * 16 + fm][fq];
    #pragma unroll
    for (int i = 0; i < WM; i++)
      #pragma unroll
      for (int j = 0; j < 4; j++)
        acc[i][j] = __builtin_amdgcn_mfma_f32_16x16x32_bf16(af[i], bfv[j], acc[i][j], 0, 0, 0);
    __syncthreads();
  }
  int col = lane & 15, rq = (lane >> 4) * 4;
  #pragma unroll
  for (int j = 0; j < 4; j++) {
    int gn = n0 + wn + j * 16 + col;
    if (gn >= N) continue;
    float bv = bias ? gload(bias, gn, fbias) : 0.f;
    #pragma unroll
    for (int i = 0; i < WM; i++) {
      #pragma unroll
      for (int r = 0; r < 4; r++) {
        int gm = m0 + wm + i * 16 + rq + r;
        float v = acc[i][j][r] * alpha + bv;
        if (doGelu) v = 0.5f * v * (1.f + erff(v * 0.70710678118f));
        size_t cx = (size_t)gm * ldc + gn;
        if (mode == 0) Cb[cx] = f2b(v);
        else if (mode == 1) Cf[cx] = v;
        else atomicAdd(Cf + cx, v);
      }
    }
  }
}

// ---- fused QKV projection: grid (48, 8, 3) ---------------------------------
__global__ __launch_bounds__(256) void qkvw_kernel(
    const bf16* __restrict__ h,
    const bf16* __restrict__ wqT, const bf16* __restrict__ wkT,
    const bf16* __restrict__ wvT,
    bf16* __restrict__ q, bf16* __restrict__ k, bf16* __restrict__ v) {
  int z = blockIdx.z;
  const bf16* W = (z == 0) ? wqT : (z == 1) ? wkT : wvT;
  bf16* C = (z == 0) ? q : (z == 1) ? k : v;
  float alpha = (z == 0) ? QSCALE : 1.f;
  gemm_bt_body<4>(h, DIM, W, DIM, blockIdx.y * 128, blockIdx.x * 128, 0, DIM,
                  INNER, alpha, nullptr, 0, 0, C, nullptr, 0, INNER);
}

// ---- sim = q @ k^T per (b,h): grid (4, 8, 16), f32 out ---------------------
__global__ __launch_bounds__(256) void simw_kernel(
    const bf16* __restrict__ q, const bf16* __restrict__ k,
    float* __restrict__ sim) {
  int z = blockIdx.z;
  size_t hoff = (size_t)(z >> 3) * SEQ * INNER + (size_t)(z & 7) * DH;
  gemm_bt_body<2>(q + hoff, INNER, k + hoff, INNER,
                  blockIdx.y * 64, blockIdx.x * 128, 0, DH, SEQ,
                  1.f, nullptr, 0, 0, nullptr, sim + (size_t)z * SEQ * SEQ, 1, SEQ);
}

// ---- o = P @ v per (b,h): grid (6, 8, 16) ----------------------------------
__global__ __launch_bounds__(256) void avw_kernel(
    const bf16* __restrict__ P, const bf16* __restrict__ vT,
    bf16* __restrict__ o) {
  int z = blockIdx.z;
  bf16* Cz = o + (size_t)(z >> 3) * SEQ * INNER + (size_t)(z & 7) * DH;
  gemm_bt_body<2>(P + (size_t)z * SEQ * 1024, 1024,
                  vT + (size_t)z * DH * SEQ, SEQ,
                  blockIdx.y * 64, blockIdx.x * 128, 0, SEQ, DH,
                  1.f, nullptr, 0, 0, Cz, nullptr, 0, INNER);
}

// ---- generic linear: grid (ceil(N/128), 8, kSplit) -------------------------
__global__ __launch_bounds__(256) void linw_kernel(
    const bf16* __restrict__ A, int lda,
    const bf16* __restrict__ Bt, int ldb,
    const void* __restrict__ biasBase, size_t biasOff,
    bf16* __restrict__ Cb, float* __restrict__ Cf, int mode, int ldc,
    int N, int K, int Kc, float alpha, int doGelu,
    const int* __restrict__ flagp) {
  int f = *flagp;
  const void* bias = nullptr;
  if (biasBase && blockIdx.z == 0)
    bias = (const void*)((const char*)biasBase + biasOff * (size_t)(f ? 2 : 4));
  int kbeg = blockIdx.z * Kc;
  int kend = min(K, kbeg + Kc);
  gemm_bt_body<4>(A, lda, Bt, ldb, blockIdx.y * 128, blockIdx.x * 128,
                  kbeg, kend, N, alpha, bias, f, doGelu, Cb, Cf, mode, ldc);
}

// ---------------- host-side orchestration ----------------
extern "C" void kernel_launch(void* const* d_in, const int* in_sizes, int n_in,
                              void* d_out, int out_size, void* d_ws, size_t ws_size,
                              hipStream_t stream) {
  const void* in_x    = d_in[0];
  const void* gam_a   = d_in[1];
  const void* Wq      = d_in[2];
  const void* Wk      = d_in[3];
  const void* Wv      = d_in[4];
  const void* Wo      = d_in[5];
  const void* gam_m   = d_in[6];
  const void* W1      = d_in[7];
  const void* b1      = d_in[8];
  const void* W2      = d_in[9];
  const void* b2      = d_in[10];
  const void* gam_mid = d_in[11];
  const void* gam_fin = d_in[12];

  // ---- workspace carving ----
  const size_t szCommon =
      256 +                                   // flag
      (size_t)TOK * DIM * 4 + 256 +           // x
      (size_t)TOK * DIM * 2 + 256 +           // h
      3 * ((size_t)TOK * INNER * 2 + 256) +   // q, k, v
      (size_t)16 * DH * SEQ * 2 + 256 +       // vT
      (size_t)16 * SEQ * SEQ * 4 + 256 +      // sim (P in place)
      (size_t)TOK * HIDN * 2 + 256;           // hid
  const size_t szWqkv1 = (size_t)INNER * DIM * 2;    // one layer, one matrix
  const size_t szW121  = (size_t)DIM * HIDN * 2;
  const size_t szWfull = 4 * 15 * szWqkv1 + 2 * 10 * szW121;
  const size_t szWmini = 4 * szWqkv1 + 2 * szW121;
  bool full = ws_size >= szCommon + szWfull + 4096;

  char* wsb = (char*)d_ws;
  size_t off = 0;
  auto carve = [&](size_t bytes) {
    char* p = wsb + off;
    off += (bytes + 255) & ~(size_t)255;
    return p;
  };
  int*   flag = (int*)carve(256);
  float* x    = (float*)carve((size_t)TOK * DIM * 4);
  bf16*  h    = (bf16*)carve((size_t)TOK * DIM * 2);
  bf16*  q    = (bf16*)carve((size_t)TOK * INNER * 2);   // reused as o
  bf16*  k    = (bf16*)carve((size_t)TOK * INNER * 2);
  bf16*  v    = (bf16*)carve((size_t)TOK * INNER * 2);
  bf16*  vT   = (bf16*)carve((size_t)16 * DH * SEQ * 2);
  float* sim  = (float*)carve((size_t)16 * SEQ * SEQ * 4); // P in place
  bf16*  hid  = (bf16*)carve((size_t)TOK * HIDN * 2);
  bf16*  o    = q;
  bf16*  P    = (bf16*)sim;
  int nw = full ? 15 : 1;
  int nm = full ? 10 : 1;
  bf16* wqT = (bf16*)carve((size_t)nw * INNER * DIM * 2);
  bf16* wkT = (bf16*)carve((size_t)nw * INNER * DIM * 2);
  bf16* wvT = (bf16*)carve((size_t)nw * INNER * DIM * 2);
  bf16* woT = (bf16*)carve((size_t)nw * INNER * DIM * 2);
  bf16* w1T = (bf16*)carve((size_t)nm * DIM * HIDN * 2);
  bf16* w2T = (bf16*)carve((size_t)nm * DIM * HIDN * 2);
  (void)szWmini;

  detect_kernel<<<dim3(1), dim3(256), 0, stream>>>(in_x, flag);
  cast_kernel<<<dim3((TOK * DIM + 255) / 256), dim3(256), 0, stream>>>(in_x, x, TOK * DIM, flag);

  if (full) {
    // one-shot weight transposes: [R][C] -> bf16 [C][R] per batch
    wtrans_kernel<<<dim3(192, 3, 15), dim3(256), 0, stream>>>(Wq, 0, DIM, INNER, wqT, flag);
    wtrans_kernel<<<dim3(192, 3, 15), dim3(256), 0, stream>>>(Wk, 0, DIM, INNER, wkT, flag);
    wtrans_kernel<<<dim3(192, 3, 15), dim3(256), 0, stream>>>(Wv, 0, DIM, INNER, wvT, flag);
    wtrans_kernel<<<dim3(3, 192, 15), dim3(256), 0, stream>>>(Wo, 0, INNER, DIM, woT, flag);
    wtrans_kernel<<<dim3(12, 3, 10), dim3(256), 0, stream>>>(W1, 0, DIM, HIDN, w1T, flag);
    wtrans_kernel<<<dim3(3, 12, 10), dim3(256), 0, stream>>>(W2, 0, HIDN, DIM, w2T, flag);
  }

  auto attn = [&](int d, int j) {
    size_t gi = ((size_t)d * 3 + j);
    bf16 *aq, *ak, *av, *ao;
    if (full) {
      aq = wqT + gi * (size_t)INNER * DIM;
      ak = wkT + gi * (size_t)INNER * DIM;
      av = wvT + gi * (size_t)INNER * DIM;
      ao = woT + gi * (size_t)INNER * DIM;
    } else {
      aq = wqT; ak = wkT; av = wvT; ao = woT;
      size_t so = gi * (size_t)DIM * INNER;
      wtrans_kernel<<<dim3(192, 3, 1), dim3(256), 0, stream>>>(Wq, so, DIM, INNER, aq, flag);
      wtrans_kernel<<<dim3(192, 3, 1), dim3(256), 0, stream>>>(Wk, so, DIM, INNER, ak, flag);
      wtrans_kernel<<<dim3(192, 3, 1), dim3(256), 0, stream>>>(Wv, so, DIM, INNER, av, flag);
      wtrans_kernel<<<dim3(3, 192, 1), dim3(256), 0, stream>>>(Wo, so, INNER, DIM, ao, flag);
    }
    ln_kernel<<<dim3(TOK / 4), dim3(256), 0, stream>>>(x, gam_a, gi * DIM, h, nullptr, TOK, 0, flag);
    qkvw_kernel<<<dim3(48, 8, 3), dim3(256), 0, stream>>>(h, aq, ak, av, q, k, v);
    simw_kernel<<<dim3(4, 8, 16), dim3(256), 0, stream>>>(q, k, sim);
    softmax_kernel<<<dim3(16 * SEQ / 4), dim3(256), 0, stream>>>(sim);
    vtrans_kernel<<<dim3(24, 16, 16), dim3(256), 0, stream>>>(v, vT);
    avw_kernel<<<dim3(6, 8, 16), dim3(256), 0, stream>>>(P, vT, o);
    // x += o @ Wo : N=96, K=6144, split-K 16 x 384
    linw_kernel<<<dim3(1, 8, 16), dim3(256), 0, stream>>>(
        o, INNER, ao, INNER, nullptr, 0,
        nullptr, x, 2, DIM, DIM, INNER, 384, 1.f, 0, flag);
  };

  auto mlp = [&](int d, int i) {
    size_t gi = ((size_t)d * 2 + i);
    bf16 *a1, *a2;
    if (full) {
      a1 = w1T + gi * (size_t)DIM * HIDN;
      a2 = w2T + gi * (size_t)DIM * HIDN;
    } else {
      a1 = w1T; a2 = w2T;
      size_t so = gi * (size_t)DIM * HIDN;
      wtrans_kernel<<<dim3(12, 3, 1), dim3(256), 0, stream>>>(W1, so, DIM, HIDN, a1, flag);
      wtrans_kernel<<<dim3(3, 12, 1), dim3(256), 0, stream>>>(W2, so, HIDN, DIM, a2, flag);
    }
    ln_kernel<<<dim3(TOK / 4), dim3(256), 0, stream>>>(x, gam_m, gi * DIM, h, nullptr, TOK, 0, flag);
    // hid = gelu(h @ W1 + b1): N=384, K=96
    linw_kernel<<<dim3(3, 8, 1), dim3(256), 0, stream>>>(
        h, DIM, a1, DIM, b1, gi * HIDN,
        hid, nullptr, 0, HIDN, HIDN, DIM, DIM, 1.f, 1, flag);
    // x += hid @ W2 + b2: N=96, K=384, split-K 4 x 96
    linw_kernel<<<dim3(1, 8, 4), dim3(256), 0, stream>>>(
        hid, HIDN, a2, HIDN, b2, gi * DIM,
        nullptr, x, 2, DIM, DIM, HIDN, 96, 1.f, 0, flag);
  };

  for (int d = 0; d < NDEPTH; d++) {
    attn(d, 0);
    mlp(d, 0);
    attn(d, 1);
    attn(d, 2);
    ln_kernel<<<dim3(TOK / 4), dim3(256), 0, stream>>>(x, gam_mid, (size_t)d * DIM, nullptr, x, TOK, 0, flag);
    mlp(d, 1);
  }
  ln_kernel<<<dim3(TOK / 4), dim3(256), 0, stream>>>(x, gam_fin, 0, d_out, nullptr, TOK, 1, flag);
}

// Round 5
// 1514.263 us; speedup vs baseline: 4.4778x; 1.4318x over previous
//
#include <hip/hip_runtime.h>
#include <hip/hip_bf16.h>

typedef __hip_bfloat16 bf16;
typedef __attribute__((ext_vector_type(8))) short bf16x8;   // 8 bf16 = 4 VGPRs
typedef __attribute__((ext_vector_type(4))) float f32x4;

#define TOK    1024
#define DIM    96
#define HIDN   384
#define HEADS  8
#define DH     768
#define INNER  6144
#define SEQ    512
#define NDEPTH 5
#define EPSLN  1e-5f
#define QSCALE 0.125f

__device__ __forceinline__ float b2f(bf16 v) { return __bfloat162float(v); }
__device__ __forceinline__ bf16  f2b(float v) { return __float2bfloat16(v); }

// Load element i from an external input buffer: f==1 -> bf16, f==0 -> fp32.
__device__ __forceinline__ float gload(const void* p, size_t i, int f) {
  return f ? b2f(((const bf16*)p)[i]) : ((const float*)p)[i];
}

// ---------------- dtype detector (bf16 vs fp32 external buffers) ------------
__global__ __launch_bounds__(256) void detect_kernel(const void* xraw, int* flag) {
  __shared__ int cnt[256];
  int t = threadIdx.x;
  const unsigned short* u = (const unsigned short*)xraw;
  int c = 0;
  #pragma unroll
  for (int i = 0; i < 4; i++) {
    unsigned short h = u[2 * (t * 4 + i)];
    int e = (h >> 7) & 0xFF;
    if (e >= 87 && e <= 132) c++;
  }
  cnt[t] = c;
  __syncthreads();
  for (int s = 128; s > 0; s >>= 1) {
    if (t < s) cnt[t] += cnt[t + s];
    __syncthreads();
  }
  if (t == 0) *flag = (cnt[0] > 700) ? 1 : 0;
}

// ---------------- cast input x -> fp32 ----------------
__global__ __launch_bounds__(256) void cast_kernel(const void* __restrict__ in,
                                                   float* __restrict__ out, int n,
                                                   const int* __restrict__ flagp) {
  int f = *flagp;
  int i = blockIdx.x * blockDim.x + threadIdx.x;
  if (i < n) out[i] = gload(in, i, f);
}

// ---------------- cast external weight -> bf16 copy (same layout) -----------
__global__ __launch_bounds__(256) void castw_kernel(const void* __restrict__ in,
                                                    bf16* __restrict__ out, int n,
                                                    const int* __restrict__ flagp) {
  int f = *flagp;
  int i0 = (blockIdx.x * blockDim.x + threadIdx.x) * 4;
  #pragma unroll
  for (int j = 0; j < 4; j++) {
    int i = i0 + j;
    if (i < n) out[i] = f2b(gload(in, i, f));
  }
}

// ---------------- weight transpose+convert: [bz][R][C] -> bf16 [bz][C][R] ---
__global__ __launch_bounds__(256) void wtrans_kernel(
    const void* __restrict__ src, int R, int C,
    bf16* __restrict__ dst, const int* __restrict__ flagp) {
  __shared__ float tile[32][33];
  int f = *flagp;
  int t = threadIdx.x;
  int tx = t & 31, ty = t >> 5;
  int c0 = blockIdx.x * 32, r0 = blockIdx.y * 32;
  size_t bb = (size_t)blockIdx.z * R * C;
  #pragma unroll
  for (int i = 0; i < 4; i++) {
    int r = r0 + ty + 8 * i, c = c0 + tx;
    float v = 0.f;
    if (r < R && c < C) v = gload(src, bb + (size_t)r * C + c, f);
    tile[ty + 8 * i][tx] = v;
  }
  __syncthreads();
  #pragma unroll
  for (int i = 0; i < 4; i++) {
    int cc = c0 + ty + 8 * i, rr = r0 + tx;
    if (cc < C && rr < R)
      dst[bb + (size_t)cc * R + rr] = f2b(tile[tx][ty + 8 * i]);
  }
}

// ---------------- LayerNorm over rows of length 96 ----------------
__global__ __launch_bounds__(256) void ln_kernel(
    const float* __restrict__ X, const void* __restrict__ gbase, size_t goff,
    void* __restrict__ outb, float* __restrict__ outf, int rows, int extout,
    const int* __restrict__ flagp) {
  int f = *flagp;
  const char* g = (const char*)gbase + goff * (size_t)(f ? 2 : 4);
  int row  = blockIdx.x * 4 + (threadIdx.x >> 6);
  int lane = threadIdx.x & 63;
  if (row >= rows) return;
  const float* xr = X + (size_t)row * DIM;
  float v0 = xr[lane];
  float v1 = (lane < 32) ? xr[64 + lane] : 0.f;
  float s = v0 + v1;
  #pragma unroll
  for (int off = 32; off > 0; off >>= 1) s += __shfl_xor(s, off);
  float mu = s * (1.f / 96.f);
  float d0 = v0 - mu;
  float d1 = (lane < 32) ? (v1 - mu) : 0.f;
  float q = d0 * d0 + d1 * d1;
  #pragma unroll
  for (int off = 32; off > 0; off >>= 1) q += __shfl_xor(q, off);
  float rstd = rsqrtf(q * (1.f / 96.f) + EPSLN);
  bool w32 = (extout && !f);
  float g0 = gload(g, lane, f) + 1.f;
  float o0 = d0 * rstd * g0;
  size_t base = (size_t)row * DIM;
  if (outb) {
    if (w32) ((float*)outb)[base + lane] = o0;
    else     ((bf16*)outb)[base + lane] = f2b(o0);
  }
  if (outf) outf[base + lane] = o0;
  if (lane < 32) {
    float g1 = gload(g, 64 + lane, f) + 1.f;
    float o1 = d1 * rstd * g1;
    if (outb) {
      if (w32) ((float*)outb)[base + 64 + lane] = o1;
      else     ((bf16*)outb)[base + 64 + lane] = f2b(o1);
    }
    if (outf) outf[base + 64 + lane] = o1;
  }
}

// =================== MFMA GEMM body — BT form (B is bf16 [N][K]) ============
// Block 256 = 4 waves (2x2). WM = wave m-frags (4 -> 128x128 tile, 2 -> 64x128).
// A rows clamped to Mtot (epilogue guards gm < Mtot); N guarded.
// mode: 0 = bf16 store Cb; 1 = f32 store Cf; 2 = f32 atomicAdd Cf.
template <int WM>
__device__ __forceinline__ void gemm_bt_body(
    const bf16* __restrict__ A, int lda,
    const bf16* __restrict__ Bt, int ldb,
    int m0, int n0, int kbeg, int kend, int Mtot, int N,
    float alpha, const void* __restrict__ bias, int fbias, int doGelu,
    bf16* __restrict__ Cb, float* __restrict__ Cf, int mode, int ldc) {
  constexpr int TM = WM * 32;
  __shared__ bf16 As[TM][40];
  __shared__ bf16 Bs[128][40];
  int t = threadIdx.x;
  int lane = t & 63;
  int wave = t >> 6;
  int wm = (wave >> 1) * (WM * 16), wn = (wave & 1) * 64;
  f32x4 acc[WM][4];
  #pragma unroll
  for (int i = 0; i < WM; i++)
    #pragma unroll
    for (int j = 0; j < 4; j++) acc[i][j] = (f32x4){0.f, 0.f, 0.f, 0.f};

  int arow = t >> 2, aseg = (t & 3) * 8;

  for (int kb = kbeg; kb < kend; kb += 32) {
    #pragma unroll
    for (int i = 0; i < TM / 64; i++) {
      int gm = min(m0 + arow + i * 64, Mtot - 1);
      *(uint4*)&As[arow + i * 64][aseg] =
          *(const uint4*)(A + (size_t)gm * lda + kb + aseg);
    }
    #pragma unroll
    for (int i = 0; i < 2; i++) {
      int r = arow + i * 64;
      int gn = n0 + r;
      uint4 val = {0, 0, 0, 0};
      if (gn < N) val = *(const uint4*)(Bt + (size_t)gn * ldb + kb + aseg);
      *(uint4*)&Bs[r][aseg] = val;
    }
    __syncthreads();
    int fm = lane & 15, fq = (lane >> 4) * 8;
    bf16x8 af[WM], bfv[4];
    #pragma unroll
    for (int i = 0; i < WM; i++)
      af[i] = *(const bf16x8*)&As[wm + i * 16 + fm][fq];
    #pragma unroll
    for (int j = 0; j < 4; j++)
      bfv[j] = *(const bf16x8*)&Bs[wn + j * 16 + fm][fq];
    #pragma unroll
    for (int i = 0; i < WM; i++)
      #pragma unroll
      for (int j = 0; j < 4; j++)
        acc[i][j] = __builtin_amdgcn_mfma_f32_16x16x32_bf16(af[i], bfv[j], acc[i][j], 0, 0, 0);
    __syncthreads();
  }
  int col = lane & 15, rq = (lane >> 4) * 4;
  #pragma unroll
  for (int j = 0; j < 4; j++) {
    int gn = n0 + wn + j * 16 + col;
    if (gn >= N) continue;
    float bv = bias ? gload(bias, gn, fbias) : 0.f;
    #pragma unroll
    for (int i = 0; i < WM; i++) {
      #pragma unroll
      for (int r = 0; r < 4; r++) {
        int gm = m0 + wm + i * 16 + rq + r;
        if (gm >= Mtot) continue;
        float v = acc[i][j][r] * alpha + bv;
        if (doGelu) v = 0.5f * v * (1.f + erff(v * 0.70710678118f));
        size_t cx = (size_t)gm * ldc + gn;
        if (mode == 0) Cb[cx] = f2b(v);
        else if (mode == 1) Cf[cx] = v;
        else atomicAdd(Cf + cx, v);
      }
    }
  }
}

// ---- precompute Mt (z<120) and Gt (z>=120): grid (1, 2, 240) ---------------
// Mt[c'][c] = 0.125 * sum_d Wk_h[c'][d] * Wq_h[c][d]   (so t = hn @ M uses Bt=Mt)
// Gt[j][c]  = sum_d WoT_h[j][d] * Wv_h[c][d]           (G[c][j] = sum Wv Wo)
__global__ __launch_bounds__(256) void mtgt_kernel(
    const bf16* __restrict__ wqB, const bf16* __restrict__ wkB,
    const bf16* __restrict__ wvB, const bf16* __restrict__ woT,
    bf16* __restrict__ Mt, bf16* __restrict__ Gt) {
  int z = blockIdx.z;
  bool isM = z < 120;
  int zz = isM ? z : z - 120;
  int L = zz >> 3, h = zz & 7;
  size_t wo = (size_t)L * DIM * INNER + (size_t)h * DH;
  const bf16* A  = isM ? (wkB + wo) : (woT + wo);
  const bf16* Bt = isM ? (wqB + wo) : (wvB + wo);
  bf16* C = (isM ? Mt : Gt) + (size_t)zz * DIM * DIM;
  gemm_bt_body<2>(A, INNER, Bt, INNER, blockIdx.y * 64, 0, 0, DH, DIM, DIM,
                  isM ? QSCALE : 1.f, nullptr, 0, 0, C, nullptr, 0, DIM);
}

// ---- t_bh = hn_b @ M_h : grid (1, 8, 16), out [16][512][96] bf16 -----------
__global__ __launch_bounds__(256) void tproj_kernel(
    const bf16* __restrict__ hn, const bf16* __restrict__ MtL,
    bf16* __restrict__ t) {
  int z = blockIdx.z, b = z >> 3, h = z & 7;
  gemm_bt_body<2>(hn + (size_t)b * SEQ * DIM, DIM,
                  MtL + (size_t)h * DIM * DIM, DIM,
                  blockIdx.y * 64, 0, 0, DIM, SEQ, DIM,
                  1.f, nullptr, 0, 0,
                  t + (size_t)z * SEQ * DIM, nullptr, 0, DIM);
}

// ---- fused S = t @ hn^T + row softmax -> P bf16 : grid (1, 8, 16) ----------
// Block: 64 q-rows x full 512 cols; 4 waves each cover 128 cols.
__global__ __launch_bounds__(256) void fattn_kernel(
    const bf16* __restrict__ t, const bf16* __restrict__ hn,
    bf16* __restrict__ P) {
  __shared__ bf16 As[64][40];
  __shared__ bf16 Bs[512][40];
  __shared__ float red[2][4][64];
  int z = blockIdx.z, b = z >> 3;
  const bf16* Az = t + (size_t)z * SEQ * DIM + (size_t)blockIdx.y * 64 * DIM;
  const bf16* Bz = hn + (size_t)b * SEQ * DIM;
  int tid = threadIdx.x, lane = tid & 63, wave = tid >> 6;
  int wn = wave * 128;
  f32x4 acc[4][8];
  #pragma unroll
  for (int i = 0; i < 4; i++)
    #pragma unroll
    for (int j = 0; j < 8; j++) acc[i][j] = (f32x4){0.f, 0.f, 0.f, 0.f};
  int arow = tid >> 2, aseg = (tid & 3) * 8;
  for (int kb = 0; kb < DIM; kb += 32) {
    *(uint4*)&As[arow][aseg] = *(const uint4*)(Az + (size_t)arow * DIM + kb + aseg);
    #pragma unroll
    for (int i = 0; i < 8; i++)
      *(uint4*)&Bs[arow + i * 64][aseg] =
          *(const uint4*)(Bz + (size_t)(arow + i * 64) * DIM + kb + aseg);
    __syncthreads();
    int fm = lane & 15, fq = (lane >> 4) * 8;
    bf16x8 af[4], bfv[8];
    #pragma unroll
    for (int i = 0; i < 4; i++)
      af[i] = *(const bf16x8*)&As[i * 16 + fm][fq];
    #pragma unroll
    for (int j = 0; j < 8; j++)
      bfv[j] = *(const bf16x8*)&Bs[wn + j * 16 + fm][fq];
    #pragma unroll
    for (int i = 0; i < 4; i++)
      #pragma unroll
      for (int j = 0; j < 8; j++)
        acc[i][j] = __builtin_amdgcn_mfma_f32_16x16x32_bf16(af[i], bfv[j], acc[i][j], 0, 0, 0);
    __syncthreads();
  }
  // ---- row softmax over 512 cols (4 waves x 128 cols each) ----
  int col = lane & 15, rq = (lane >> 4) * 4;
  float rmax[4][4];
  #pragma unroll
  for (int i = 0; i < 4; i++)
    #pragma unroll
    for (int r = 0; r < 4; r++) {
      float m = -1e30f;
      #pragma unroll
      for (int j = 0; j < 8; j++) m = fmaxf(m, acc[i][j][r]);
      rmax[i][r] = m;
    }
  #pragma unroll
  for (int s = 1; s < 16; s <<= 1)
    #pragma unroll
    for (int i = 0; i < 4; i++)
      #pragma unroll
      for (int r = 0; r < 4; r++)
        rmax[i][r] = fmaxf(rmax[i][r], __shfl_xor(rmax[i][r], s));
  if (col == 0)
    #pragma unroll
    for (int i = 0; i < 4; i++)
      #pragma unroll
      for (int r = 0; r < 4; r++) red[0][wave][i * 16 + rq + r] = rmax[i][r];
  __syncthreads();
  float gmax[4][4];
  #pragma unroll
  for (int i = 0; i < 4; i++)
    #pragma unroll
    for (int r = 0; r < 4; r++) {
      int row = i * 16 + rq + r;
      gmax[i][r] = fmaxf(fmaxf(red[0][0][row], red[0][1][row]),
                         fmaxf(red[0][2][row], red[0][3][row]));
    }
  float rsum[4][4];
  #pragma unroll
  for (int i = 0; i < 4; i++)
    #pragma unroll
    for (int r = 0; r < 4; r++) {
      float s = 0.f;
      #pragma unroll
      for (int j = 0; j < 8; j++) {
        float e = __expf(acc[i][j][r] - gmax[i][r]);
        acc[i][j][r] = e;
        s += e;
      }
      rsum[i][r] = s;
    }
  #pragma unroll
  for (int s = 1; s < 16; s <<= 1)
    #pragma unroll
    for (int i = 0; i < 4; i++)
      #pragma unroll
      for (int r = 0; r < 4; r++)
        rsum[i][r] += __shfl_xor(rsum[i][r], s);
  if (col == 0)
    #pragma unroll
    for (int i = 0; i < 4; i++)
      #pragma unroll
      for (int r = 0; r < 4; r++) red[1][wave][i * 16 + rq + r] = rsum[i][r];
  __syncthreads();
  bf16* Pz = P + (size_t)z * SEQ * SEQ + (size_t)blockIdx.y * 64 * SEQ;
  #pragma unroll
  for (int i = 0; i < 4; i++)
    #pragma unroll
    for (int r = 0; r < 4; r++) {
      int row = i * 16 + rq + r;
      float tot = red[1][0][row] + red[1][1][row] + red[1][2][row] + red[1][3][row];
      float inv = 1.f / tot;
      #pragma unroll
      for (int j = 0; j < 8; j++)
        Pz[(size_t)row * SEQ + wn + j * 16 + col] = f2b(acc[i][j][r] * inv);
    }
}

// ---- W~T_bh = Gt_h @ hn_b^T : grid (4, 2, 16), out [16][96][512] bf16 ------
__global__ __launch_bounds__(256) void wtld_kernel(
    const bf16* __restrict__ GtL, const bf16* __restrict__ hn,
    bf16* __restrict__ wt) {
  int z = blockIdx.z, b = z >> 3, h = z & 7;
  gemm_bt_body<2>(GtL + (size_t)h * DIM * DIM, DIM,
                  hn + (size_t)b * SEQ * DIM, DIM,
                  blockIdx.y * 64, blockIdx.x * 128, 0, DIM, DIM, SEQ,
                  1.f, nullptr, 0, 0,
                  wt + (size_t)z * DIM * SEQ, nullptr, 0, SEQ);
}

// ---- x += P_bh @ W~_bh : grid (1, 8, 16), f32 atomicAdd --------------------
__global__ __launch_bounds__(256) void pw_kernel(
    const bf16* __restrict__ P, const bf16* __restrict__ wt,
    float* __restrict__ x) {
  int z = blockIdx.z, b = z >> 3;
  gemm_bt_body<2>(P + (size_t)z * SEQ * SEQ, SEQ,
                  wt + (size_t)z * DIM * SEQ, SEQ,
                  blockIdx.y * 64, 0, 0, SEQ, SEQ, DIM,
                  1.f, nullptr, 0, 0,
                  nullptr, x + (size_t)b * SEQ * DIM, 2, DIM);
}

// ---- generic linear for MLP: grid (ceil(N/128), 8, kSplit) -----------------
__global__ __launch_bounds__(256) void linw_kernel(
    const bf16* __restrict__ A, int lda,
    const bf16* __restrict__ Bt, int ldb,
    const void* __restrict__ biasBase, size_t biasOff,
    bf16* __restrict__ Cb, float* __restrict__ Cf, int mode, int ldc,
    int N, int K, int Kc, float alpha, int doGelu,
    const int* __restrict__ flagp) {
  int f = *flagp;
  const void* bias = nullptr;
  if (biasBase && blockIdx.z == 0)
    bias = (const void*)((const char*)biasBase + biasOff * (size_t)(f ? 2 : 4));
  int kbeg = blockIdx.z * Kc;
  int kend = min(K, kbeg + Kc);
  gemm_bt_body<4>(A, lda, Bt, ldb, blockIdx.y * 128, blockIdx.x * 128,
                  kbeg, kend, TOK, N, alpha, bias, f, doGelu, Cb, Cf, mode, ldc);
}

// ---------------- host-side orchestration ----------------
extern "C" void kernel_launch(void* const* d_in, const int* in_sizes, int n_in,
                              void* d_out, int out_size, void* d_ws, size_t ws_size,
                              hipStream_t stream) {
  const void* in_x    = d_in[0];
  const void* gam_a   = d_in[1];
  const void* Wq      = d_in[2];
  const void* Wk      = d_in[3];
  const void* Wv      = d_in[4];
  const void* Wo      = d_in[5];
  const void* gam_m   = d_in[6];
  const void* W1      = d_in[7];
  const void* b1      = d_in[8];
  const void* W2      = d_in[9];
  const void* b2      = d_in[10];
  const void* gam_mid = d_in[11];
  const void* gam_fin = d_in[12];

  char* wsb = (char*)d_ws;
  size_t off = 0;
  auto carve = [&](size_t bytes) {
    char* p = wsb + off;
    off += (bytes + 255) & ~(size_t)255;
    return p;
  };
  int*   flag = (int*)carve(256);
  float* x    = (float*)carve((size_t)TOK * DIM * 4);
  bf16*  hn   = (bf16*)carve((size_t)TOK * DIM * 2);
  bf16*  tb   = (bf16*)carve((size_t)16 * SEQ * DIM * 2);
  bf16*  P    = (bf16*)carve((size_t)16 * SEQ * SEQ * 2);
  bf16*  wt   = (bf16*)carve((size_t)16 * DIM * SEQ * 2);
  bf16*  hid  = (bf16*)carve((size_t)TOK * HIDN * 2);
  const size_t WSZ = (size_t)15 * DIM * INNER;   // per big weight, elements
  bf16*  wqB  = (bf16*)carve(WSZ * 2);
  bf16*  wkB  = (bf16*)carve(WSZ * 2);
  bf16*  wvB  = (bf16*)carve(WSZ * 2);
  bf16*  woT  = (bf16*)carve(WSZ * 2);
  bf16*  w1T  = (bf16*)carve((size_t)10 * DIM * HIDN * 2);
  bf16*  w2T  = (bf16*)carve((size_t)10 * DIM * HIDN * 2);
  bf16*  Mt   = (bf16*)carve((size_t)120 * DIM * DIM * 2);
  bf16*  Gt   = (bf16*)carve((size_t)120 * DIM * DIM * 2);

  detect_kernel<<<dim3(1), dim3(256), 0, stream>>>(in_x, flag);
  cast_kernel<<<dim3((TOK * DIM + 255) / 256), dim3(256), 0, stream>>>(in_x, x, TOK * DIM, flag);

  // ---- once-per-call weight prep ----
  int nW = (int)WSZ;
  castw_kernel<<<dim3((nW / 4 + 255) / 256), dim3(256), 0, stream>>>(Wq, wqB, nW, flag);
  castw_kernel<<<dim3((nW / 4 + 255) / 256), dim3(256), 0, stream>>>(Wk, wkB, nW, flag);
  castw_kernel<<<dim3((nW / 4 + 255) / 256), dim3(256), 0, stream>>>(Wv, wvB, nW, flag);
  wtrans_kernel<<<dim3(3, 192, 15), dim3(256), 0, stream>>>(Wo, INNER, DIM, woT, flag);
  wtrans_kernel<<<dim3(12, 3, 10), dim3(256), 0, stream>>>(W1, DIM, HIDN, w1T, flag);
  wtrans_kernel<<<dim3(3, 12, 10), dim3(256), 0, stream>>>(W2, HIDN, DIM, w2T, flag);
  mtgt_kernel<<<dim3(1, 2, 240), dim3(256), 0, stream>>>(wqB, wkB, wvB, woT, Mt, Gt);

  auto attn = [&](int d, int j) {
    size_t gi = ((size_t)d * 3 + j);
    const bf16* MtL = Mt + gi * 8 * DIM * DIM;
    const bf16* GtL = Gt + gi * 8 * DIM * DIM;
    ln_kernel<<<dim3(TOK / 4), dim3(256), 0, stream>>>(x, gam_a, gi * DIM, hn, nullptr, TOK, 0, flag);
    tproj_kernel<<<dim3(1, 8, 16), dim3(256), 0, stream>>>(hn, MtL, tb);
    fattn_kernel<<<dim3(1, 8, 16), dim3(256), 0, stream>>>(tb, hn, P);
    wtld_kernel<<<dim3(4, 2, 16), dim3(256), 0, stream>>>(GtL, hn, wt);
    pw_kernel<<<dim3(1, 8, 16), dim3(256), 0, stream>>>(P, wt, x);
  };

  auto mlp = [&](int d, int i) {
    size_t gi = ((size_t)d * 2 + i);
    bf16* a1 = w1T + gi * (size_t)DIM * HIDN;
    bf16* a2 = w2T + gi * (size_t)DIM * HIDN;
    ln_kernel<<<dim3(TOK / 4), dim3(256), 0, stream>>>(x, gam_m, gi * DIM, hn, nullptr, TOK, 0, flag);
    // hid = gelu(hn @ W1 + b1): N=384, K=96
    linw_kernel<<<dim3(3, 8, 1), dim3(256), 0, stream>>>(
        hn, DIM, a1, DIM, b1, gi * HIDN,
        hid, nullptr, 0, HIDN, HIDN, DIM, DIM, 1.f, 1, flag);
    // x += hid @ W2 + b2: N=96, K=384, split-K 4 x 96
    linw_kernel<<<dim3(1, 8, 4), dim3(256), 0, stream>>>(
        hid, HIDN, a2, HIDN, b2, gi * DIM,
        nullptr, x, 2, DIM, DIM, HIDN, 96, 1.f, 0, flag);
  };

  for (int d = 0; d < NDEPTH; d++) {
    attn(d, 0);
    mlp(d, 0);
    attn(d, 1);
    attn(d, 2);
    ln_kernel<<<dim3(TOK / 4), dim3(256), 0, stream>>>(x, gam_mid, (size_t)d * DIM, nullptr, x, TOK, 0, flag);
    mlp(d, 1);
  }
  ln_kernel<<<dim3(TOK / 4), dim3(256), 0, stream>>>(x, gam_fin, 0, d_out, nullptr, TOK, 1, flag);
}

// Round 6
// 1468.332 us; speedup vs baseline: 4.6178x; 1.0313x over previous
//
#include <hip/hip_runtime.h>
#include <hip/hip_bf16.h>

typedef __hip_bfloat16 bf16;
typedef __attribute__((ext_vector_type(8))) short bf16x8;   // 8 bf16 = 4 VGPRs
typedef __attribute__((ext_vector_type(4))) float f32x4;

#define TOK    1024
#define DIM    96
#define HIDN   384
#define HEADS  8
#define DH     768
#define INNER  6144
#define SEQ    512
#define NDEPTH 5
#define EPSLN  1e-5f
#define QSCALE 0.125f

__device__ __forceinline__ float b2f(bf16 v) { return __bfloat162float(v); }
__device__ __forceinline__ bf16  f2b(float v) { return __float2bfloat16(v); }

// Load element i from an external input buffer: f==1 -> bf16, f==0 -> fp32.
__device__ __forceinline__ float gload(const void* p, size_t i, int f) {
  return f ? b2f(((const bf16*)p)[i]) : ((const float*)p)[i];
}

// ---------------- dtype detector (bf16 vs fp32 external buffers) ------------
__global__ __launch_bounds__(256) void detect_kernel(const void* xraw, int* flag) {
  __shared__ int cnt[256];
  int t = threadIdx.x;
  const unsigned short* u = (const unsigned short*)xraw;
  int c = 0;
  #pragma unroll
  for (int i = 0; i < 4; i++) {
    unsigned short h = u[2 * (t * 4 + i)];
    int e = (h >> 7) & 0xFF;
    if (e >= 87 && e <= 132) c++;
  }
  cnt[t] = c;
  __syncthreads();
  for (int s = 128; s > 0; s >>= 1) {
    if (t < s) cnt[t] += cnt[t + s];
    __syncthreads();
  }
  if (t == 0) *flag = (cnt[0] > 700) ? 1 : 0;
}

// ---------------- cast input x -> fp32 ----------------
__global__ __launch_bounds__(256) void cast_kernel(const void* __restrict__ in,
                                                   float* __restrict__ out, int n,
                                                   const int* __restrict__ flagp) {
  int f = *flagp;
  int i = blockIdx.x * blockDim.x + threadIdx.x;
  if (i < n) out[i] = gload(in, i, f);
}

// ---------------- cast external weight -> bf16 copy (same layout) -----------
__global__ __launch_bounds__(256) void castw_kernel(const void* __restrict__ in,
                                                    bf16* __restrict__ out, int n,
                                                    const int* __restrict__ flagp) {
  int f = *flagp;
  int i0 = (blockIdx.x * blockDim.x + threadIdx.x) * 4;
  #pragma unroll
  for (int j = 0; j < 4; j++) {
    int i = i0 + j;
    if (i < n) out[i] = f2b(gload(in, i, f));
  }
}

// ---------------- weight transpose+convert: [bz][R][C] -> bf16 [bz][C][R] ---
__global__ __launch_bounds__(256) void wtrans_kernel(
    const void* __restrict__ src, int R, int C,
    bf16* __restrict__ dst, const int* __restrict__ flagp) {
  __shared__ float tile[32][33];
  int f = *flagp;
  int t = threadIdx.x;
  int tx = t & 31, ty = t >> 5;
  int c0 = blockIdx.x * 32, r0 = blockIdx.y * 32;
  size_t bb = (size_t)blockIdx.z * R * C;
  #pragma unroll
  for (int i = 0; i < 4; i++) {
    int r = r0 + ty + 8 * i, c = c0 + tx;
    float v = 0.f;
    if (r < R && c < C) v = gload(src, bb + (size_t)r * C + c, f);
    tile[ty + 8 * i][tx] = v;
  }
  __syncthreads();
  #pragma unroll
  for (int i = 0; i < 4; i++) {
    int cc = c0 + ty + 8 * i, rr = r0 + tx;
    if (cc < C && rr < R)
      dst[bb + (size_t)cc * R + rr] = f2b(tile[tx][ty + 8 * i]);
  }
}

// ---------------- LayerNorm over rows of length 96 ----------------
__global__ __launch_bounds__(256) void ln_kernel(
    const float* __restrict__ X, const void* __restrict__ gbase, size_t goff,
    void* __restrict__ outb, float* __restrict__ outf, int rows, int extout,
    const int* __restrict__ flagp) {
  int f = *flagp;
  const char* g = (const char*)gbase + goff * (size_t)(f ? 2 : 4);
  int row  = blockIdx.x * 4 + (threadIdx.x >> 6);
  int lane = threadIdx.x & 63;
  if (row >= rows) return;
  const float* xr = X + (size_t)row * DIM;
  float v0 = xr[lane];
  float v1 = (lane < 32) ? xr[64 + lane] : 0.f;
  float s = v0 + v1;
  #pragma unroll
  for (int off = 32; off > 0; off >>= 1) s += __shfl_xor(s, off);
  float mu = s * (1.f / 96.f);
  float d0 = v0 - mu;
  float d1 = (lane < 32) ? (v1 - mu) : 0.f;
  float q = d0 * d0 + d1 * d1;
  #pragma unroll
  for (int off = 32; off > 0; off >>= 1) q += __shfl_xor(q, off);
  float rstd = rsqrtf(q * (1.f / 96.f) + EPSLN);
  bool w32 = (extout && !f);
  float g0 = gload(g, lane, f) + 1.f;
  float o0 = d0 * rstd * g0;
  size_t base = (size_t)row * DIM;
  if (outb) {
    if (w32) ((float*)outb)[base + lane] = o0;
    else     ((bf16*)outb)[base + lane] = f2b(o0);
  }
  if (outf) outf[base + lane] = o0;
  if (lane < 32) {
    float g1 = gload(g, 64 + lane, f) + 1.f;
    float o1 = d1 * rstd * g1;
    if (outb) {
      if (w32) ((float*)outb)[base + 64 + lane] = o1;
      else     ((bf16*)outb)[base + 64 + lane] = f2b(o1);
    }
    if (outf) outf[base + 64 + lane] = o1;
  }
}

// =================== MFMA GEMM body — BT form (B is bf16 [N][K]) ============
// Block 256 = 4 waves (2x2). WM = wave m-frags (4 -> 128x128, 2 -> 64x128).
// mode: 0 = bf16 store Cb; 1 = f32 store Cf; 2 = f32 atomicAdd Cf.
template <int WM>
__device__ __forceinline__ void gemm_bt_body(
    const bf16* __restrict__ A, int lda,
    const bf16* __restrict__ Bt, int ldb,
    int m0, int n0, int kbeg, int kend, int Mtot, int N,
    float alpha, const void* __restrict__ bias, int fbias, int doGelu,
    bf16* __restrict__ Cb, float* __restrict__ Cf, int mode, int ldc) {
  constexpr int TM = WM * 32;
  __shared__ bf16 As[TM][40];
  __shared__ bf16 Bs[128][40];
  int t = threadIdx.x;
  int lane = t & 63;
  int wave = t >> 6;
  int wm = (wave >> 1) * (WM * 16), wn = (wave & 1) * 64;
  f32x4 acc[WM][4];
  #pragma unroll
  for (int i = 0; i < WM; i++)
    #pragma unroll
    for (int j = 0; j < 4; j++) acc[i][j] = (f32x4){0.f, 0.f, 0.f, 0.f};

  int arow = t >> 2, aseg = (t & 3) * 8;

  for (int kb = kbeg; kb < kend; kb += 32) {
    #pragma unroll
    for (int i = 0; i < TM / 64; i++) {
      int gm = min(m0 + arow + i * 64, Mtot - 1);
      *(uint4*)&As[arow + i * 64][aseg] =
          *(const uint4*)(A + (size_t)gm * lda + kb + aseg);
    }
    #pragma unroll
    for (int i = 0; i < 2; i++) {
      int r = arow + i * 64;
      int gn = n0 + r;
      uint4 val = {0, 0, 0, 0};
      if (gn < N) val = *(const uint4*)(Bt + (size_t)gn * ldb + kb + aseg);
      *(uint4*)&Bs[r][aseg] = val;
    }
    __syncthreads();
    int fm = lane & 15, fq = (lane >> 4) * 8;
    bf16x8 af[WM], bfv[4];
    #pragma unroll
    for (int i = 0; i < WM; i++)
      af[i] = *(const bf16x8*)&As[wm + i * 16 + fm][fq];
    #pragma unroll
    for (int j = 0; j < 4; j++)
      bfv[j] = *(const bf16x8*)&Bs[wn + j * 16 + fm][fq];
    #pragma unroll
    for (int i = 0; i < WM; i++)
      #pragma unroll
      for (int j = 0; j < 4; j++)
        acc[i][j] = __builtin_amdgcn_mfma_f32_16x16x32_bf16(af[i], bfv[j], acc[i][j], 0, 0, 0);
    __syncthreads();
  }
  int col = lane & 15, rq = (lane >> 4) * 4;
  #pragma unroll
  for (int j = 0; j < 4; j++) {
    int gn = n0 + wn + j * 16 + col;
    if (gn >= N) continue;
    float bv = bias ? gload(bias, gn, fbias) : 0.f;
    #pragma unroll
    for (int i = 0; i < WM; i++) {
      #pragma unroll
      for (int r = 0; r < 4; r++) {
        int gm = m0 + wm + i * 16 + rq + r;
        if (gm >= Mtot) continue;
        float v = acc[i][j][r] * alpha + bv;
        if (doGelu) v = 0.5f * v * (1.f + erff(v * 0.70710678118f));
        size_t cx = (size_t)gm * ldc + gn;
        if (mode == 0) Cb[cx] = f2b(v);
        else if (mode == 1) Cf[cx] = v;
        else atomicAdd(Cf + cx, v);
      }
    }
  }
}

// ---- precompute Mt (z<120) and Gt (z>=120): grid (1, 2, 240) ---------------
__global__ __launch_bounds__(256) void mtgt_kernel(
    const bf16* __restrict__ wqB, const bf16* __restrict__ wkB,
    const bf16* __restrict__ wvB, const bf16* __restrict__ woT,
    bf16* __restrict__ Mt, bf16* __restrict__ Gt) {
  int z = blockIdx.z;
  bool isM = z < 120;
  int zz = isM ? z : z - 120;
  int L = zz >> 3, h = zz & 7;
  size_t wo = (size_t)L * DIM * INNER + (size_t)h * DH;
  const bf16* A  = isM ? (wkB + wo) : (woT + wo);
  const bf16* Bt = isM ? (wqB + wo) : (wvB + wo);
  bf16* C = (isM ? Mt : Gt) + (size_t)zz * DIM * DIM;
  gemm_bt_body<2>(A, INNER, Bt, INNER, blockIdx.y * 64, 0, 0, DH, DIM, DIM,
                  isM ? QSCALE : 1.f, nullptr, 0, 0, C, nullptr, 0, DIM);
}

// ---- W~T_bh = Gt_h @ hn_b^T : grid (4, 2, 16), out [16][96][512] bf16 ------
__global__ __launch_bounds__(256) void wtld_kernel(
    const bf16* __restrict__ GtL, const bf16* __restrict__ hn,
    bf16* __restrict__ wt) {
  int z = blockIdx.z, b = z >> 3, h = z & 7;
  gemm_bt_body<2>(GtL + (size_t)h * DIM * DIM, DIM,
                  hn + (size_t)b * SEQ * DIM, DIM,
                  blockIdx.y * 64, blockIdx.x * 128, 0, DIM, DIM, SEQ,
                  1.f, nullptr, 0, 0,
                  wt + (size_t)z * DIM * SEQ, nullptr, 0, SEQ);
}

// ================= fused attention: t-proj + S + softmax + P@V~ =============
// grid (16, 16): x = 32-row q-tile, y = z (b*8+h). Output atomicAdd into x.
struct FS1 { bf16 As[32][104]; bf16 Mts[96][104]; };
union FU { FS1 s1; bf16 Bs2[512][40]; bf16 Bs3[96][136]; };

__global__ __launch_bounds__(256) void fattn2_kernel(
    const bf16* __restrict__ hn, const bf16* __restrict__ MtL,
    const bf16* __restrict__ wt, float* __restrict__ x) {
  __shared__ FU u;
  __shared__ bf16 tP[32][136];     // stage1-2: t[32][96]; stage3: P-chunk [32][128]
  __shared__ float red[2][4][32];
  int tid = threadIdx.x, lane = tid & 63, wave = tid >> 6;
  int fm = lane & 15, fq = (lane >> 4) * 8;
  int col = lane & 15, rq = (lane >> 4) * 4;
  int mw = wave & 1, ng = wave >> 1;          // m-frag / n-group for stages 1,3
  int z = blockIdx.y, b = z >> 3, h = z & 7;
  int m0 = blockIdx.x * 32;
  const bf16* hnB = hn + (size_t)b * SEQ * DIM;
  const bf16* MtH = MtL + (size_t)h * DIM * DIM;
  const bf16* wtz = wt + (size_t)z * DIM * SEQ;

  // ---- stage 1: t = hn_tile[32x96] @ M_h ----
  for (int idx = tid; idx < 384; idx += 256) {   // 32 x 96 / 8
    int r = idx / 12, cs = (idx % 12) * 8;
    *(uint4*)&u.s1.As[r][cs] = *(const uint4*)(hnB + (size_t)(m0 + r) * DIM + cs);
  }
  for (int idx = tid; idx < 1152; idx += 256) {  // 96 x 96 / 8
    int r = idx / 12, cs = (idx % 12) * 8;
    *(uint4*)&u.s1.Mts[r][cs] = *(const uint4*)(MtH + (size_t)r * DIM + cs);
  }
  __syncthreads();
  {
    f32x4 acc1[3];
    #pragma unroll
    for (int j = 0; j < 3; j++) acc1[j] = (f32x4){0.f, 0.f, 0.f, 0.f};
    #pragma unroll
    for (int kb = 0; kb < 96; kb += 32) {
      bf16x8 af = *(const bf16x8*)&u.s1.As[mw * 16 + fm][kb + fq];
      #pragma unroll
      for (int j = 0; j < 3; j++) {
        bf16x8 bv = *(const bf16x8*)&u.s1.Mts[(3 * ng + j) * 16 + fm][kb + fq];
        acc1[j] = __builtin_amdgcn_mfma_f32_16x16x32_bf16(af, bv, acc1[j], 0, 0, 0);
      }
    }
    __syncthreads();   // As/Mts reads done before t write reuses nothing, but sync for clarity of u reuse
    #pragma unroll
    for (int j = 0; j < 3; j++)
      #pragma unroll
      for (int r = 0; r < 4; r++)
        tP[mw * 16 + rq + r][(3 * ng + j) * 16 + col] = f2b(acc1[j][r]);
  }
  __syncthreads();

  // ---- stage 2: S = t @ hn^T  (32 x 512), wave covers cols [128w,128w+128) --
  f32x4 acc2[2][8];
  #pragma unroll
  for (int i = 0; i < 2; i++)
    #pragma unroll
    for (int j = 0; j < 8; j++) acc2[i][j] = (f32x4){0.f, 0.f, 0.f, 0.f};
  int arow = tid >> 2, aseg = (tid & 3) * 8;
  #pragma unroll
  for (int kb = 0; kb < 96; kb += 32) {
    #pragma unroll
    for (int i = 0; i < 8; i++)
      *(uint4*)&u.Bs2[arow + i * 64][aseg] =
          *(const uint4*)(hnB + (size_t)(arow + i * 64) * DIM + kb + aseg);
    __syncthreads();
    bf16x8 af[2], bv[8];
    #pragma unroll
    for (int i = 0; i < 2; i++)
      af[i] = *(const bf16x8*)&tP[i * 16 + fm][kb + fq];
    #pragma unroll
    for (int j = 0; j < 8; j++)
      bv[j] = *(const bf16x8*)&u.Bs2[wave * 128 + j * 16 + fm][fq];
    #pragma unroll
    for (int i = 0; i < 2; i++)
      #pragma unroll
      for (int j = 0; j < 8; j++)
        acc2[i][j] = __builtin_amdgcn_mfma_f32_16x16x32_bf16(af[i], bv[j], acc2[i][j], 0, 0, 0);
    __syncthreads();
  }

  // ---- softmax over 512 cols ----
  float rmax[2][4];
  #pragma unroll
  for (int i = 0; i < 2; i++)
    #pragma unroll
    for (int r = 0; r < 4; r++) {
      float m = -1e30f;
      #pragma unroll
      for (int j = 0; j < 8; j++) m = fmaxf(m, acc2[i][j][r]);
      rmax[i][r] = m;
    }
  #pragma unroll
  for (int s = 1; s < 16; s <<= 1)
    #pragma unroll
    for (int i = 0; i < 2; i++)
      #pragma unroll
      for (int r = 0; r < 4; r++)
        rmax[i][r] = fmaxf(rmax[i][r], __shfl_xor(rmax[i][r], s));
  if (col == 0)
    #pragma unroll
    for (int i = 0; i < 2; i++)
      #pragma unroll
      for (int r = 0; r < 4; r++) red[0][wave][i * 16 + rq + r] = rmax[i][r];
  __syncthreads();
  float rsum[2][4];
  #pragma unroll
  for (int i = 0; i < 2; i++)
    #pragma unroll
    for (int r = 0; r < 4; r++) {
      int row = i * 16 + rq + r;
      float gm = fmaxf(fmaxf(red[0][0][row], red[0][1][row]),
                       fmaxf(red[0][2][row], red[0][3][row]));
      float s = 0.f;
      #pragma unroll
      for (int j = 0; j < 8; j++) {
        float e = __expf(acc2[i][j][r] - gm);
        acc2[i][j][r] = e;
        s += e;
      }
      rsum[i][r] = s;
    }
  #pragma unroll
  for (int s = 1; s < 16; s <<= 1)
    #pragma unroll
    for (int i = 0; i < 2; i++)
      #pragma unroll
      for (int r = 0; r < 4; r++)
        rsum[i][r] += __shfl_xor(rsum[i][r], s);
  if (col == 0)
    #pragma unroll
    for (int i = 0; i < 2; i++)
      #pragma unroll
      for (int r = 0; r < 4; r++) red[1][wave][i * 16 + rq + r] = rsum[i][r];
  __syncthreads();

  // ---- stage 3: O = P @ V~, chunked over 4 x 128 cols ----
  f32x4 acc3[3];
  #pragma unroll
  for (int j = 0; j < 3; j++) acc3[j] = (f32x4){0.f, 0.f, 0.f, 0.f};
  for (int c = 0; c < 4; c++) {
    if (wave == c) {
      #pragma unroll
      for (int i = 0; i < 2; i++)
        #pragma unroll
        for (int r = 0; r < 4; r++) {
          int row = i * 16 + rq + r;
          float tot = red[1][0][row] + red[1][1][row] + red[1][2][row] + red[1][3][row];
          float inv = 1.f / tot;
          #pragma unroll
          for (int j = 0; j < 8; j++)
            tP[row][j * 16 + col] = f2b(acc2[i][j][r] * inv);
        }
    }
    for (int idx = tid; idx < 1536; idx += 256) {   // 96 x 128 / 8
      int r = idx >> 4, cs = (idx & 15) * 8;
      *(uint4*)&u.Bs3[r][cs] = *(const uint4*)(wtz + (size_t)r * SEQ + c * 128 + cs);
    }
    __syncthreads();
    #pragma unroll
    for (int s = 0; s < 128; s += 32) {
      bf16x8 af = *(const bf16x8*)&tP[mw * 16 + fm][s + fq];
      #pragma unroll
      for (int j = 0; j < 3; j++) {
        bf16x8 bv = *(const bf16x8*)&u.Bs3[(3 * ng + j) * 16 + fm][s + fq];
        acc3[j] = __builtin_amdgcn_mfma_f32_16x16x32_bf16(af, bv, acc3[j], 0, 0, 0);
      }
    }
    __syncthreads();
  }
  // epilogue: atomicAdd into x
  #pragma unroll
  for (int j = 0; j < 3; j++) {
    int cn = (3 * ng + j) * 16 + col;
    #pragma unroll
    for (int r = 0; r < 4; r++) {
      int gr = b * SEQ + m0 + mw * 16 + rq + r;
      atomicAdd(x + (size_t)gr * DIM + cn, acc3[j][r]);
    }
  }
}

// ================= fused MLP stage 1: LN + GEMM(+bias+GELU) =================
// grid (3, 8): x = n-tile (128 of 384), y = m-tile (128 rows of 1024).
__global__ __launch_bounds__(256) void mlp1_kernel(
    const float* __restrict__ X, const void* __restrict__ gbase, size_t goff,
    const bf16* __restrict__ w1T, const void* __restrict__ b1base, size_t b1off,
    bf16* __restrict__ hid, const int* __restrict__ flagp) {
  __shared__ bf16 As[128][104];
  __shared__ bf16 Bs[128][40];
  int f = *flagp;
  int tid = threadIdx.x, lane = tid & 63, wave = tid >> 6;
  int m0 = blockIdx.y * 128, n0 = blockIdx.x * 128;
  const char* g = (const char*)gbase + goff * (size_t)(f ? 2 : 4);
  float g0 = gload(g, lane, f) + 1.f;
  float g1 = (lane < 32) ? (gload(g, 64 + lane, f) + 1.f) : 0.f;
  for (int r = wave; r < 128; r += 4) {
    const float* xr = X + (size_t)(m0 + r) * DIM;
    float v0 = xr[lane];
    float v1 = (lane < 32) ? xr[64 + lane] : 0.f;
    float s = v0 + v1;
    #pragma unroll
    for (int off = 32; off > 0; off >>= 1) s += __shfl_xor(s, off);
    float mu = s * (1.f / 96.f);
    float d0 = v0 - mu;
    float d1 = (lane < 32) ? (v1 - mu) : 0.f;
    float q = d0 * d0 + d1 * d1;
    #pragma unroll
    for (int off = 32; off > 0; off >>= 1) q += __shfl_xor(q, off);
    float rstd = rsqrtf(q * (1.f / 96.f) + EPSLN);
    As[r][lane] = f2b(d0 * rstd * g0);
    if (lane < 32) As[r][64 + lane] = f2b(d1 * rstd * g1);
  }
  __syncthreads();
  int fm = lane & 15, fq = (lane >> 4) * 8;
  int wm = (wave >> 1) * 64, wn = (wave & 1) * 64;
  f32x4 acc[4][4];
  #pragma unroll
  for (int i = 0; i < 4; i++)
    #pragma unroll
    for (int j = 0; j < 4; j++) acc[i][j] = (f32x4){0.f, 0.f, 0.f, 0.f};
  int arow = tid >> 2, aseg = (tid & 3) * 8;
  #pragma unroll
  for (int kb = 0; kb < 96; kb += 32) {
    #pragma unroll
    for (int i = 0; i < 2; i++)
      *(uint4*)&Bs[arow + i * 64][aseg] =
          *(const uint4*)(w1T + (size_t)(n0 + arow + i * 64) * DIM + kb + aseg);
    __syncthreads();
    bf16x8 af[4], bv[4];
    #pragma unroll
    for (int i = 0; i < 4; i++)
      af[i] = *(const bf16x8*)&As[wm + i * 16 + fm][kb + fq];
    #pragma unroll
    for (int j = 0; j < 4; j++)
      bv[j] = *(const bf16x8*)&Bs[wn + j * 16 + fm][fq];
    #pragma unroll
    for (int i = 0; i < 4; i++)
      #pragma unroll
      for (int j = 0; j < 4; j++)
        acc[i][j] = __builtin_amdgcn_mfma_f32_16x16x32_bf16(af[i], bv[j], acc[i][j], 0, 0, 0);
    __syncthreads();
  }
  int col = lane & 15, rq = (lane >> 4) * 4;
  const char* bb = (const char*)b1base + b1off * (size_t)(f ? 2 : 4);
  #pragma unroll
  for (int j = 0; j < 4; j++) {
    int gn = n0 + wn + j * 16 + col;
    float bv = gload(bb, gn, f);
    #pragma unroll
    for (int i = 0; i < 4; i++)
      #pragma unroll
      for (int r = 0; r < 4; r++) {
        int gm = m0 + wm + i * 16 + rq + r;
        float v = acc[i][j][r] + bv;
        v = 0.5f * v * (1.f + erff(v * 0.70710678118f));
        hid[(size_t)gm * HIDN + gn] = f2b(v);
      }
  }
}

// ---- generic linear (mlp2): grid (ceil(N/128), 8, kSplit) ------------------
__global__ __launch_bounds__(256) void linw_kernel(
    const bf16* __restrict__ A, int lda,
    const bf16* __restrict__ Bt, int ldb,
    const void* __restrict__ biasBase, size_t biasOff,
    bf16* __restrict__ Cb, float* __restrict__ Cf, int mode, int ldc,
    int N, int K, int Kc, float alpha, int doGelu,
    const int* __restrict__ flagp) {
  int f = *flagp;
  const void* bias = nullptr;
  if (biasBase && blockIdx.z == 0)
    bias = (const void*)((const char*)biasBase + biasOff * (size_t)(f ? 2 : 4));
  int kbeg = blockIdx.z * Kc;
  int kend = min(K, kbeg + Kc);
  gemm_bt_body<4>(A, lda, Bt, ldb, blockIdx.y * 128, blockIdx.x * 128,
                  kbeg, kend, TOK, N, alpha, bias, f, doGelu, Cb, Cf, mode, ldc);
}

// ---------------- host-side orchestration ----------------
extern "C" void kernel_launch(void* const* d_in, const int* in_sizes, int n_in,
                              void* d_out, int out_size, void* d_ws, size_t ws_size,
                              hipStream_t stream) {
  const void* in_x    = d_in[0];
  const void* gam_a   = d_in[1];
  const void* Wq      = d_in[2];
  const void* Wk      = d_in[3];
  const void* Wv      = d_in[4];
  const void* Wo      = d_in[5];
  const void* gam_m   = d_in[6];
  const void* W1      = d_in[7];
  const void* b1      = d_in[8];
  const void* W2      = d_in[9];
  const void* b2      = d_in[10];
  const void* gam_mid = d_in[11];
  const void* gam_fin = d_in[12];

  char* wsb = (char*)d_ws;
  size_t off = 0;
  auto carve = [&](size_t bytes) {
    char* p = wsb + off;
    off += (bytes + 255) & ~(size_t)255;
    return p;
  };
  int*   flag = (int*)carve(256);
  float* x    = (float*)carve((size_t)TOK * DIM * 4);
  bf16*  hn   = (bf16*)carve((size_t)TOK * DIM * 2);
  bf16*  wt   = (bf16*)carve((size_t)16 * DIM * SEQ * 2);
  bf16*  hid  = (bf16*)carve((size_t)TOK * HIDN * 2);
  const size_t WSZ = (size_t)15 * DIM * INNER;   // per big weight, elements
  bf16*  wqB  = (bf16*)carve(WSZ * 2);
  bf16*  wkB  = (bf16*)carve(WSZ * 2);
  bf16*  wvB  = (bf16*)carve(WSZ * 2);
  bf16*  woT  = (bf16*)carve(WSZ * 2);
  bf16*  w1T  = (bf16*)carve((size_t)10 * DIM * HIDN * 2);
  bf16*  w2T  = (bf16*)carve((size_t)10 * DIM * HIDN * 2);
  bf16*  Mt   = (bf16*)carve((size_t)120 * DIM * DIM * 2);
  bf16*  Gt   = (bf16*)carve((size_t)120 * DIM * DIM * 2);

  detect_kernel<<<dim3(1), dim3(256), 0, stream>>>(in_x, flag);
  cast_kernel<<<dim3((TOK * DIM + 255) / 256), dim3(256), 0, stream>>>(in_x, x, TOK * DIM, flag);

  // ---- once-per-call weight prep ----
  int nW = (int)WSZ;
  castw_kernel<<<dim3((nW / 4 + 255) / 256), dim3(256), 0, stream>>>(Wq, wqB, nW, flag);
  castw_kernel<<<dim3((nW / 4 + 255) / 256), dim3(256), 0, stream>>>(Wk, wkB, nW, flag);
  castw_kernel<<<dim3((nW / 4 + 255) / 256), dim3(256), 0, stream>>>(Wv, wvB, nW, flag);
  wtrans_kernel<<<dim3(3, 192, 15), dim3(256), 0, stream>>>(Wo, INNER, DIM, woT, flag);
  wtrans_kernel<<<dim3(12, 3, 10), dim3(256), 0, stream>>>(W1, DIM, HIDN, w1T, flag);
  wtrans_kernel<<<dim3(3, 12, 10), dim3(256), 0, stream>>>(W2, HIDN, DIM, w2T, flag);
  mtgt_kernel<<<dim3(1, 2, 240), dim3(256), 0, stream>>>(wqB, wkB, wvB, woT, Mt, Gt);

  auto attn = [&](int d, int j) {
    size_t gi = ((size_t)d * 3 + j);
    const bf16* MtL = Mt + gi * 8 * DIM * DIM;
    const bf16* GtL = Gt + gi * 8 * DIM * DIM;
    ln_kernel<<<dim3(TOK / 4), dim3(256), 0, stream>>>(x, gam_a, gi * DIM, hn, nullptr, TOK, 0, flag);
    wtld_kernel<<<dim3(4, 2, 16), dim3(256), 0, stream>>>(GtL, hn, wt);
    fattn2_kernel<<<dim3(16, 16), dim3(256), 0, stream>>>(hn, MtL, wt, x);
  };

  auto mlp = [&](int d, int i) {
    size_t gi = ((size_t)d * 2 + i);
    bf16* a1 = w1T + gi * (size_t)DIM * HIDN;
    bf16* a2 = w2T + gi * (size_t)DIM * HIDN;
    mlp1_kernel<<<dim3(3, 8), dim3(256), 0, stream>>>(
        x, gam_m, gi * DIM, a1, b1, gi * HIDN, hid, flag);
    // x += hid @ W2 + b2: N=96, K=384, split-K 4 x 96
    linw_kernel<<<dim3(1, 8, 4), dim3(256), 0, stream>>>(
        hid, HIDN, a2, HIDN, b2, gi * DIM,
        nullptr, x, 2, DIM, DIM, HIDN, 96, 1.f, 0, flag);
  };

  for (int d = 0; d < NDEPTH; d++) {
    attn(d, 0);
    mlp(d, 0);
    attn(d, 1);
    attn(d, 2);
    ln_kernel<<<dim3(TOK / 4), dim3(256), 0, stream>>>(x, gam_mid, (size_t)d * DIM, nullptr, x, TOK, 0, flag);
    mlp(d, 1);
  }
  ln_kernel<<<dim3(TOK / 4), dim3(256), 0, stream>>>(x, gam_fin, 0, d_out, nullptr, TOK, 1, flag);
}

// Round 7
// 996.766 us; speedup vs baseline: 6.8025x; 1.4731x over previous
//
#include <hip/hip_runtime.h>
#include <hip/hip_bf16.h>

typedef __hip_bfloat16 bf16;
typedef __attribute__((ext_vector_type(8))) short bf16x8;   // 8 bf16 = 4 VGPRs
typedef __attribute__((ext_vector_type(4))) float f32x4;

#define TOK    1024
#define DIM    96
#define HIDN   384
#define HEADS  8
#define DH     768
#define INNER  6144
#define SEQ    512
#define NDEPTH 5
#define EPSLN  1e-5f
#define QSCALE 0.125f

__device__ __forceinline__ float b2f(bf16 v) { return __bfloat162float(v); }
__device__ __forceinline__ bf16  f2b(float v) { return __float2bfloat16(v); }

// Load element i from an external input buffer: f==1 -> bf16, f==0 -> fp32.
__device__ __forceinline__ float gload(const void* p, size_t i, int f) {
  return f ? b2f(((const bf16*)p)[i]) : ((const float*)p)[i];
}

// ---------------- dtype detector (bf16 vs fp32 external buffers) ------------
__global__ __launch_bounds__(256) void detect_kernel(const void* xraw, int* flag) {
  __shared__ int cnt[256];
  int t = threadIdx.x;
  const unsigned short* u = (const unsigned short*)xraw;
  int c = 0;
  #pragma unroll
  for (int i = 0; i < 4; i++) {
    unsigned short h = u[2 * (t * 4 + i)];
    int e = (h >> 7) & 0xFF;
    if (e >= 87 && e <= 132) c++;
  }
  cnt[t] = c;
  __syncthreads();
  for (int s = 128; s > 0; s >>= 1) {
    if (t < s) cnt[t] += cnt[t + s];
    __syncthreads();
  }
  if (t == 0) *flag = (cnt[0] > 700) ? 1 : 0;
}

// ---------------- cast input x -> fp32 ----------------
__global__ __launch_bounds__(256) void cast_kernel(const void* __restrict__ in,
                                                   float* __restrict__ out, int n,
                                                   const int* __restrict__ flagp) {
  int f = *flagp;
  int i = blockIdx.x * blockDim.x + threadIdx.x;
  if (i < n) out[i] = gload(in, i, f);
}

// ---------------- cast external weight -> bf16 copy (same layout) -----------
__global__ __launch_bounds__(256) void castw_kernel(const void* __restrict__ in,
                                                    bf16* __restrict__ out, int n,
                                                    const int* __restrict__ flagp) {
  int f = *flagp;
  int i0 = (blockIdx.x * blockDim.x + threadIdx.x) * 4;
  #pragma unroll
  for (int j = 0; j < 4; j++) {
    int i = i0 + j;
    if (i < n) out[i] = f2b(gload(in, i, f));
  }
}

// ---------------- weight transpose+convert: [bz][R][C] -> bf16 [bz][C][R] ---
__global__ __launch_bounds__(256) void wtrans_kernel(
    const void* __restrict__ src, int R, int C,
    bf16* __restrict__ dst, const int* __restrict__ flagp) {
  __shared__ float tile[32][33];
  int f = *flagp;
  int t = threadIdx.x;
  int tx = t & 31, ty = t >> 5;
  int c0 = blockIdx.x * 32, r0 = blockIdx.y * 32;
  size_t bb = (size_t)blockIdx.z * R * C;
  #pragma unroll
  for (int i = 0; i < 4; i++) {
    int r = r0 + ty + 8 * i, c = c0 + tx;
    float v = 0.f;
    if (r < R && c < C) v = gload(src, bb + (size_t)r * C + c, f);
    tile[ty + 8 * i][tx] = v;
  }
  __syncthreads();
  #pragma unroll
  for (int i = 0; i < 4; i++) {
    int cc = c0 + ty + 8 * i, rr = r0 + tx;
    if (cc < C && rr < R)
      dst[bb + (size_t)cc * R + rr] = f2b(tile[tx][ty + 8 * i]);
  }
}

// ---------------- LayerNorm over rows of length 96 ----------------
__global__ __launch_bounds__(256) void ln_kernel(
    const float* __restrict__ X, const void* __restrict__ gbase, size_t goff,
    void* __restrict__ outb, float* __restrict__ outf, int rows, int extout,
    const int* __restrict__ flagp) {
  int f = *flagp;
  const char* g = (const char*)gbase + goff * (size_t)(f ? 2 : 4);
  int row  = blockIdx.x * 4 + (threadIdx.x >> 6);
  int lane = threadIdx.x & 63;
  if (row >= rows) return;
  const float* xr = X + (size_t)row * DIM;
  float v0 = xr[lane];
  float v1 = (lane < 32) ? xr[64 + lane] : 0.f;
  float s = v0 + v1;
  #pragma unroll
  for (int off = 32; off > 0; off >>= 1) s += __shfl_xor(s, off);
  float mu = s * (1.f / 96.f);
  float d0 = v0 - mu;
  float d1 = (lane < 32) ? (v1 - mu) : 0.f;
  float q = d0 * d0 + d1 * d1;
  #pragma unroll
  for (int off = 32; off > 0; off >>= 1) q += __shfl_xor(q, off);
  float rstd = rsqrtf(q * (1.f / 96.f) + EPSLN);
  bool w32 = (extout && !f);
  float g0 = gload(g, lane, f) + 1.f;
  float o0 = d0 * rstd * g0;
  size_t base = (size_t)row * DIM;
  if (outb) {
    if (w32) ((float*)outb)[base + lane] = o0;
    else     ((bf16*)outb)[base + lane] = f2b(o0);
  }
  if (outf) outf[base + lane] = o0;
  if (lane < 32) {
    float g1 = gload(g, 64 + lane, f) + 1.f;
    float o1 = d1 * rstd * g1;
    if (outb) {
      if (w32) ((float*)outb)[base + 64 + lane] = o1;
      else     ((bf16*)outb)[base + 64 + lane] = f2b(o1);
    }
    if (outf) outf[base + 64 + lane] = o1;
  }
}

// =================== MFMA GEMM body — BT form (B is bf16 [N][K]) ============
// Block 256 = 4 waves (2x2). WM = wave m-frags; TM = WM*32 (1->32, 2->64, 4->128).
// mode: 0 = bf16 store Cb; 1 = f32 store Cf; 2 = f32 atomicAdd Cf.
template <int WM>
__device__ __forceinline__ void gemm_bt_body(
    const bf16* __restrict__ A, int lda,
    const bf16* __restrict__ Bt, int ldb,
    int m0, int n0, int kbeg, int kend, int Mtot, int N,
    float alpha, const void* __restrict__ bias, int fbias, int doGelu,
    bf16* __restrict__ Cb, float* __restrict__ Cf, int mode, int ldc) {
  constexpr int TM = WM * 32;
  __shared__ bf16 As[TM][40];
  __shared__ bf16 Bs[128][40];
  int t = threadIdx.x;
  int lane = t & 63;
  int wave = t >> 6;
  int wm = (wave >> 1) * (WM * 16), wn = (wave & 1) * 64;
  f32x4 acc[WM][4];
  #pragma unroll
  for (int i = 0; i < WM; i++)
    #pragma unroll
    for (int j = 0; j < 4; j++) acc[i][j] = (f32x4){0.f, 0.f, 0.f, 0.f};

  int arow = t >> 2, aseg = (t & 3) * 8;

  for (int kb = kbeg; kb < kend; kb += 32) {
    if constexpr (TM >= 64) {
      #pragma unroll
      for (int i = 0; i < TM / 64; i++) {
        int gm = min(m0 + arow + i * 64, Mtot - 1);
        *(uint4*)&As[arow + i * 64][aseg] =
            *(const uint4*)(A + (size_t)gm * lda + kb + aseg);
      }
    } else {
      if (arow < TM) {
        int gm = min(m0 + arow, Mtot - 1);
        *(uint4*)&As[arow][aseg] =
            *(const uint4*)(A + (size_t)gm * lda + kb + aseg);
      }
    }
    #pragma unroll
    for (int i = 0; i < 2; i++) {
      int r = arow + i * 64;
      int gn = n0 + r;
      uint4 val = {0, 0, 0, 0};
      if (gn < N) val = *(const uint4*)(Bt + (size_t)gn * ldb + kb + aseg);
      *(uint4*)&Bs[r][aseg] = val;
    }
    __syncthreads();
    int fm = lane & 15, fq = (lane >> 4) * 8;
    bf16x8 af[WM], bfv[4];
    #pragma unroll
    for (int i = 0; i < WM; i++)
      af[i] = *(const bf16x8*)&As[wm + i * 16 + fm][fq];
    #pragma unroll
    for (int j = 0; j < 4; j++)
      bfv[j] = *(const bf16x8*)&Bs[wn + j * 16 + fm][fq];
    #pragma unroll
    for (int i = 0; i < WM; i++)
      #pragma unroll
      for (int j = 0; j < 4; j++)
        acc[i][j] = __builtin_amdgcn_mfma_f32_16x16x32_bf16(af[i], bfv[j], acc[i][j], 0, 0, 0);
    __syncthreads();
  }
  int col = lane & 15, rq = (lane >> 4) * 4;
  #pragma unroll
  for (int j = 0; j < 4; j++) {
    int gn = n0 + wn + j * 16 + col;
    if (gn >= N) continue;
    float bv = bias ? gload(bias, gn, fbias) : 0.f;
    #pragma unroll
    for (int i = 0; i < WM; i++) {
      #pragma unroll
      for (int r = 0; r < 4; r++) {
        int gm = m0 + wm + i * 16 + rq + r;
        if (gm >= Mtot) continue;
        float v = acc[i][j][r] * alpha + bv;
        if (doGelu) v = 0.5f * v * (1.f + erff(v * 0.70710678118f));
        size_t cx = (size_t)gm * ldc + gn;
        if (mode == 0) Cb[cx] = f2b(v);
        else if (mode == 1) Cf[cx] = v;
        else atomicAdd(Cf + cx, v);
      }
    }
  }
}

// ---- precompute Mt (z<120) and Gt (z>=120): grid (1, 2, 240) ---------------
__global__ __launch_bounds__(256) void mtgt_kernel(
    const bf16* __restrict__ wqB, const bf16* __restrict__ wkB,
    const bf16* __restrict__ wvB, const bf16* __restrict__ woT,
    bf16* __restrict__ Mt, bf16* __restrict__ Gt) {
  int z = blockIdx.z;
  bool isM = z < 120;
  int zz = isM ? z : z - 120;
  int L = zz >> 3, h = zz & 7;
  size_t wo = (size_t)L * DIM * INNER + (size_t)h * DH;
  const bf16* A  = isM ? (wkB + wo) : (woT + wo);
  const bf16* Bt = isM ? (wqB + wo) : (wvB + wo);
  bf16* C = (isM ? Mt : Gt) + (size_t)zz * DIM * DIM;
  gemm_bt_body<2>(A, INNER, Bt, INNER, blockIdx.y * 64, 0, 0, DH, DIM, DIM,
                  isM ? QSCALE : 1.f, nullptr, 0, 0, C, nullptr, 0, DIM);
}

// ---- W~T_bh = Gt_h @ hn_b^T : grid (4, 2, 16), out [16][96][512] bf16 ------
__global__ __launch_bounds__(256) void wtld_kernel(
    const bf16* __restrict__ GtL, const bf16* __restrict__ hn,
    bf16* __restrict__ wt) {
  int z = blockIdx.z, b = z >> 3, h = z & 7;
  gemm_bt_body<2>(GtL + (size_t)h * DIM * DIM, DIM,
                  hn + (size_t)b * SEQ * DIM, DIM,
                  blockIdx.y * 64, blockIdx.x * 128, 0, DIM, DIM, SEQ,
                  1.f, nullptr, 0, 0,
                  wt + (size_t)z * DIM * SEQ, nullptr, 0, SEQ);
}

// ================= fused attention: t-proj + S + softmax + P@V~ =============
// grid (16, 16): x = 32-row q-tile, y = z (b*8+h). Output atomicAdd into x.
struct FS1 { bf16 As[32][104]; bf16 Mts[96][104]; };
union FU { FS1 s1; bf16 Bs2[512][40]; bf16 Bs3[96][136]; };

__global__ __launch_bounds__(256) void fattn2_kernel(
    const bf16* __restrict__ hn, const bf16* __restrict__ MtL,
    const bf16* __restrict__ wt, float* __restrict__ x) {
  __shared__ FU u;
  __shared__ bf16 tP[32][136];     // stage1-2: t[32][96]; stage3: P-chunk [32][128]
  __shared__ float red[2][4][32];
  int tid = threadIdx.x, lane = tid & 63, wave = tid >> 6;
  int fm = lane & 15, fq = (lane >> 4) * 8;
  int col = lane & 15, rq = (lane >> 4) * 4;
  int mw = wave & 1, ng = wave >> 1;          // m-frag / n-group for stages 1,3
  int z = blockIdx.y, b = z >> 3, h = z & 7;
  int m0 = blockIdx.x * 32;
  const bf16* hnB = hn + (size_t)b * SEQ * DIM;
  const bf16* MtH = MtL + (size_t)h * DIM * DIM;
  const bf16* wtz = wt + (size_t)z * DIM * SEQ;

  // ---- stage 1: t = hn_tile[32x96] @ M_h ----
  for (int idx = tid; idx < 384; idx += 256) {   // 32 x 96 / 8
    int r = idx / 12, cs = (idx % 12) * 8;
    *(uint4*)&u.s1.As[r][cs] = *(const uint4*)(hnB + (size_t)(m0 + r) * DIM + cs);
  }
  for (int idx = tid; idx < 1152; idx += 256) {  // 96 x 96 / 8
    int r = idx / 12, cs = (idx % 12) * 8;
    *(uint4*)&u.s1.Mts[r][cs] = *(const uint4*)(MtH + (size_t)r * DIM + cs);
  }
  __syncthreads();
  {
    f32x4 acc1[3];
    #pragma unroll
    for (int j = 0; j < 3; j++) acc1[j] = (f32x4){0.f, 0.f, 0.f, 0.f};
    #pragma unroll
    for (int kb = 0; kb < 96; kb += 32) {
      bf16x8 af = *(const bf16x8*)&u.s1.As[mw * 16 + fm][kb + fq];
      #pragma unroll
      for (int j = 0; j < 3; j++) {
        bf16x8 bv = *(const bf16x8*)&u.s1.Mts[(3 * ng + j) * 16 + fm][kb + fq];
        acc1[j] = __builtin_amdgcn_mfma_f32_16x16x32_bf16(af, bv, acc1[j], 0, 0, 0);
      }
    }
    __syncthreads();
    #pragma unroll
    for (int j = 0; j < 3; j++)
      #pragma unroll
      for (int r = 0; r < 4; r++)
        tP[mw * 16 + rq + r][(3 * ng + j) * 16 + col] = f2b(acc1[j][r]);
  }
  __syncthreads();

  // ---- stage 2: S = t @ hn^T  (32 x 512), wave covers cols [128w,128w+128) --
  f32x4 acc2[2][8];
  #pragma unroll
  for (int i = 0; i < 2; i++)
    #pragma unroll
    for (int j = 0; j < 8; j++) acc2[i][j] = (f32x4){0.f, 0.f, 0.f, 0.f};
  int arow = tid >> 2, aseg = (tid & 3) * 8;
  #pragma unroll
  for (int kb = 0; kb < 96; kb += 32) {
    #pragma unroll
    for (int i = 0; i < 8; i++)
      *(uint4*)&u.Bs2[arow + i * 64][aseg] =
          *(const uint4*)(hnB + (size_t)(arow + i * 64) * DIM + kb + aseg);
    __syncthreads();
    bf16x8 af[2], bv[8];
    #pragma unroll
    for (int i = 0; i < 2; i++)
      af[i] = *(const bf16x8*)&tP[i * 16 + fm][kb + fq];
    #pragma unroll
    for (int j = 0; j < 8; j++)
      bv[j] = *(const bf16x8*)&u.Bs2[wave * 128 + j * 16 + fm][fq];
    #pragma unroll
    for (int i = 0; i < 2; i++)
      #pragma unroll
      for (int j = 0; j < 8; j++)
        acc2[i][j] = __builtin_amdgcn_mfma_f32_16x16x32_bf16(af[i], bv[j], acc2[i][j], 0, 0, 0);
    __syncthreads();
  }

  // ---- softmax over 512 cols ----
  float rmax[2][4];
  #pragma unroll
  for (int i = 0; i < 2; i++)
    #pragma unroll
    for (int r = 0; r < 4; r++) {
      float m = -1e30f;
      #pragma unroll
      for (int j = 0; j < 8; j++) m = fmaxf(m, acc2[i][j][r]);
      rmax[i][r] = m;
    }
  #pragma unroll
  for (int s = 1; s < 16; s <<= 1)
    #pragma unroll
    for (int i = 0; i < 2; i++)
      #pragma unroll
      for (int r = 0; r < 4; r++)
        rmax[i][r] = fmaxf(rmax[i][r], __shfl_xor(rmax[i][r], s));
  if (col == 0)
    #pragma unroll
    for (int i = 0; i < 2; i++)
      #pragma unroll
      for (int r = 0; r < 4; r++) red[0][wave][i * 16 + rq + r] = rmax[i][r];
  __syncthreads();
  float rsum[2][4];
  #pragma unroll
  for (int i = 0; i < 2; i++)
    #pragma unroll
    for (int r = 0; r < 4; r++) {
      int row = i * 16 + rq + r;
      float gm = fmaxf(fmaxf(red[0][0][row], red[0][1][row]),
                       fmaxf(red[0][2][row], red[0][3][row]));
      float s = 0.f;
      #pragma unroll
      for (int j = 0; j < 8; j++) {
        float e = __expf(acc2[i][j][r] - gm);
        acc2[i][j][r] = e;
        s += e;
      }
      rsum[i][r] = s;
    }
  #pragma unroll
  for (int s = 1; s < 16; s <<= 1)
    #pragma unroll
    for (int i = 0; i < 2; i++)
      #pragma unroll
      for (int r = 0; r < 4; r++)
        rsum[i][r] += __shfl_xor(rsum[i][r], s);
  if (col == 0)
    #pragma unroll
    for (int i = 0; i < 2; i++)
      #pragma unroll
      for (int r = 0; r < 4; r++) red[1][wave][i * 16 + rq + r] = rsum[i][r];
  __syncthreads();

  // ---- stage 3: O = P @ V~, chunked over 4 x 128 cols ----
  f32x4 acc3[3];
  #pragma unroll
  for (int j = 0; j < 3; j++) acc3[j] = (f32x4){0.f, 0.f, 0.f, 0.f};
  for (int c = 0; c < 4; c++) {
    if (wave == c) {
      #pragma unroll
      for (int i = 0; i < 2; i++)
        #pragma unroll
        for (int r = 0; r < 4; r++) {
          int row = i * 16 + rq + r;
          float tot = red[1][0][row] + red[1][1][row] + red[1][2][row] + red[1][3][row];
          float inv = 1.f / tot;
          #pragma unroll
          for (int j = 0; j < 8; j++)
            tP[row][j * 16 + col] = f2b(acc2[i][j][r] * inv);
        }
    }
    for (int idx = tid; idx < 1536; idx += 256) {   // 96 x 128 / 8
      int r = idx >> 4, cs = (idx & 15) * 8;
      *(uint4*)&u.Bs3[r][cs] = *(const uint4*)(wtz + (size_t)r * SEQ + c * 128 + cs);
    }
    __syncthreads();
    #pragma unroll
    for (int s = 0; s < 128; s += 32) {
      bf16x8 af = *(const bf16x8*)&tP[mw * 16 + fm][s + fq];
      #pragma unroll
      for (int j = 0; j < 3; j++) {
        bf16x8 bv = *(const bf16x8*)&u.Bs3[(3 * ng + j) * 16 + fm][s + fq];
        acc3[j] = __builtin_amdgcn_mfma_f32_16x16x32_bf16(af, bv, acc3[j], 0, 0, 0);
      }
    }
    __syncthreads();
  }
  // epilogue: atomicAdd into x
  #pragma unroll
  for (int j = 0; j < 3; j++) {
    int cn = (3 * ng + j) * 16 + col;
    #pragma unroll
    for (int r = 0; r < 4; r++) {
      int gr = b * SEQ + m0 + mw * 16 + rq + r;
      atomicAdd(x + (size_t)gr * DIM + cn, acc3[j][r]);
    }
  }
}

// ================= fused MLP stage 1: LN + GEMM(+bias+GELU), TM=32 ==========
// grid (3, 32): x = n-tile (128 of 384), y = m-tile (32 rows of 1024).
__global__ __launch_bounds__(256) void mlp1_kernel(
    const float* __restrict__ X, const void* __restrict__ gbase, size_t goff,
    const bf16* __restrict__ w1T, const void* __restrict__ b1base, size_t b1off,
    bf16* __restrict__ hid, const int* __restrict__ flagp) {
  __shared__ bf16 As[32][104];
  __shared__ bf16 Bs[128][40];
  int f = *flagp;
  int tid = threadIdx.x, lane = tid & 63, wave = tid >> 6;
  int m0 = blockIdx.y * 32, n0 = blockIdx.x * 128;
  const char* g = (const char*)gbase + goff * (size_t)(f ? 2 : 4);
  float g0 = gload(g, lane, f) + 1.f;
  float g1 = (lane < 32) ? (gload(g, 64 + lane, f) + 1.f) : 0.f;
  for (int r = wave; r < 32; r += 4) {
    const float* xr = X + (size_t)(m0 + r) * DIM;
    float v0 = xr[lane];
    float v1 = (lane < 32) ? xr[64 + lane] : 0.f;
    float s = v0 + v1;
    #pragma unroll
    for (int off = 32; off > 0; off >>= 1) s += __shfl_xor(s, off);
    float mu = s * (1.f / 96.f);
    float d0 = v0 - mu;
    float d1 = (lane < 32) ? (v1 - mu) : 0.f;
    float q = d0 * d0 + d1 * d1;
    #pragma unroll
    for (int off = 32; off > 0; off >>= 1) q += __shfl_xor(q, off);
    float rstd = rsqrtf(q * (1.f / 96.f) + EPSLN);
    As[r][lane] = f2b(d0 * rstd * g0);
    if (lane < 32) As[r][64 + lane] = f2b(d1 * rstd * g1);
  }
  __syncthreads();
  int fm = lane & 15, fq = (lane >> 4) * 8;
  int wm = (wave >> 1) * 16, wn = (wave & 1) * 64;
  f32x4 acc[4];
  #pragma unroll
  for (int j = 0; j < 4; j++) acc[j] = (f32x4){0.f, 0.f, 0.f, 0.f};
  int arow = tid >> 2, aseg = (tid & 3) * 8;
  #pragma unroll
  for (int kb = 0; kb < 96; kb += 32) {
    #pragma unroll
    for (int i = 0; i < 2; i++)
      *(uint4*)&Bs[arow + i * 64][aseg] =
          *(const uint4*)(w1T + (size_t)(n0 + arow + i * 64) * DIM + kb + aseg);
    __syncthreads();
    bf16x8 af = *(const bf16x8*)&As[wm + fm][kb + fq];
    bf16x8 bv[4];
    #pragma unroll
    for (int j = 0; j < 4; j++)
      bv[j] = *(const bf16x8*)&Bs[wn + j * 16 + fm][fq];
    #pragma unroll
    for (int j = 0; j < 4; j++)
      acc[j] = __builtin_amdgcn_mfma_f32_16x16x32_bf16(af, bv[j], acc[j], 0, 0, 0);
    __syncthreads();
  }
  int col = lane & 15, rq = (lane >> 4) * 4;
  const char* bb = (const char*)b1base + b1off * (size_t)(f ? 2 : 4);
  #pragma unroll
  for (int j = 0; j < 4; j++) {
    int gn = n0 + wn + j * 16 + col;
    float bv = gload(bb, gn, f);
    #pragma unroll
    for (int r = 0; r < 4; r++) {
      int gm = m0 + wm + rq + r;
      float v = acc[j][r] + bv;
      v = 0.5f * v * (1.f + erff(v * 0.70710678118f));
      hid[(size_t)gm * HIDN + gn] = f2b(v);
    }
  }
}

// ---- generic linear: grid (ceil(N/128), M/(WM*32), kSplit) -----------------
template <int WM>
__global__ __launch_bounds__(256) void linw_kernel(
    const bf16* __restrict__ A, int lda,
    const bf16* __restrict__ Bt, int ldb,
    const void* __restrict__ biasBase, size_t biasOff,
    bf16* __restrict__ Cb, float* __restrict__ Cf, int mode, int ldc,
    int N, int K, int Kc, float alpha, int doGelu,
    const int* __restrict__ flagp) {
  int f = *flagp;
  const void* bias = nullptr;
  if (biasBase && blockIdx.z == 0)
    bias = (const void*)((const char*)biasBase + biasOff * (size_t)(f ? 2 : 4));
  int kbeg = blockIdx.z * Kc;
  int kend = min(K, kbeg + Kc);
  gemm_bt_body<WM>(A, lda, Bt, ldb, blockIdx.y * (WM * 32), blockIdx.x * 128,
                   kbeg, kend, TOK, N, alpha, bias, f, doGelu, Cb, Cf, mode, ldc);
}

// ---------------- host-side orchestration ----------------
extern "C" void kernel_launch(void* const* d_in, const int* in_sizes, int n_in,
                              void* d_out, int out_size, void* d_ws, size_t ws_size,
                              hipStream_t stream) {
  const void* in_x    = d_in[0];
  const void* gam_a   = d_in[1];
  const void* Wq      = d_in[2];
  const void* Wk      = d_in[3];
  const void* Wv      = d_in[4];
  const void* Wo      = d_in[5];
  const void* gam_m   = d_in[6];
  const void* W1      = d_in[7];
  const void* b1      = d_in[8];
  const void* W2      = d_in[9];
  const void* b2      = d_in[10];
  const void* gam_mid = d_in[11];
  const void* gam_fin = d_in[12];

  char* wsb = (char*)d_ws;
  size_t off = 0;
  auto carve = [&](size_t bytes) {
    char* p = wsb + off;
    off += (bytes + 255) & ~(size_t)255;
    return p;
  };
  int*   flag = (int*)carve(256);
  float* x    = (float*)carve((size_t)TOK * DIM * 4);
  bf16*  hn   = (bf16*)carve((size_t)TOK * DIM * 2);
  bf16*  wt   = (bf16*)carve((size_t)16 * DIM * SEQ * 2);
  bf16*  hid  = (bf16*)carve((size_t)TOK * HIDN * 2);
  const size_t WSZ = (size_t)15 * DIM * INNER;   // per big weight, elements
  bf16*  wqB  = (bf16*)carve(WSZ * 2);
  bf16*  wkB  = (bf16*)carve(WSZ * 2);
  bf16*  wvB  = (bf16*)carve(WSZ * 2);
  bf16*  woT  = (bf16*)carve(WSZ * 2);
  bf16*  w1T  = (bf16*)carve((size_t)10 * DIM * HIDN * 2);
  bf16*  w2T  = (bf16*)carve((size_t)10 * DIM * HIDN * 2);
  bf16*  Mt   = (bf16*)carve((size_t)120 * DIM * DIM * 2);
  bf16*  Gt   = (bf16*)carve((size_t)120 * DIM * DIM * 2);

  detect_kernel<<<dim3(1), dim3(256), 0, stream>>>(in_x, flag);
  cast_kernel<<<dim3((TOK * DIM + 255) / 256), dim3(256), 0, stream>>>(in_x, x, TOK * DIM, flag);

  // ---- once-per-call weight prep ----
  int nW = (int)WSZ;
  castw_kernel<<<dim3((nW / 4 + 255) / 256), dim3(256), 0, stream>>>(Wq, wqB, nW, flag);
  castw_kernel<<<dim3((nW / 4 + 255) / 256), dim3(256), 0, stream>>>(Wk, wkB, nW, flag);
  castw_kernel<<<dim3((nW / 4 + 255) / 256), dim3(256), 0, stream>>>(Wv, wvB, nW, flag);
  wtrans_kernel<<<dim3(3, 192, 15), dim3(256), 0, stream>>>(Wo, INNER, DIM, woT, flag);
  wtrans_kernel<<<dim3(12, 3, 10), dim3(256), 0, stream>>>(W1, DIM, HIDN, w1T, flag);
  wtrans_kernel<<<dim3(3, 12, 10), dim3(256), 0, stream>>>(W2, HIDN, DIM, w2T, flag);
  mtgt_kernel<<<dim3(1, 2, 240), dim3(256), 0, stream>>>(wqB, wkB, wvB, woT, Mt, Gt);

  auto attn = [&](int d, int j) {
    size_t gi = ((size_t)d * 3 + j);
    const bf16* MtL = Mt + gi * 8 * DIM * DIM;
    const bf16* GtL = Gt + gi * 8 * DIM * DIM;
    ln_kernel<<<dim3(TOK / 4), dim3(256), 0, stream>>>(x, gam_a, gi * DIM, hn, nullptr, TOK, 0, flag);
    wtld_kernel<<<dim3(4, 2, 16), dim3(256), 0, stream>>>(GtL, hn, wt);
    fattn2_kernel<<<dim3(16, 16), dim3(256), 0, stream>>>(hn, MtL, wt, x);
  };

  auto mlp = [&](int d, int i) {
    size_t gi = ((size_t)d * 2 + i);
    bf16* a1 = w1T + gi * (size_t)DIM * HIDN;
    bf16* a2 = w2T + gi * (size_t)DIM * HIDN;
    mlp1_kernel<<<dim3(3, 32), dim3(256), 0, stream>>>(
        x, gam_m, gi * DIM, a1, b1, gi * HIDN, hid, flag);
    // x += hid @ W2 + b2: N=96, K=384, split-K 4 x 96, 32-row m-tiles
    linw_kernel<1><<<dim3(1, 32, 4), dim3(256), 0, stream>>>(
        hid, HIDN, a2, HIDN, b2, gi * DIM,
        nullptr, x, 2, DIM, DIM, HIDN, 96, 1.f, 0, flag);
  };

  for (int d = 0; d < NDEPTH; d++) {
    attn(d, 0);
    mlp(d, 0);
    attn(d, 1);
    attn(d, 2);
    ln_kernel<<<dim3(TOK / 4), dim3(256), 0, stream>>>(x, gam_mid, (size_t)d * DIM, nullptr, x, TOK, 0, flag);
    mlp(d, 1);
  }
  ln_kernel<<<dim3(TOK / 4), dim3(256), 0, stream>>>(x, gam_fin, 0, d_out, nullptr, TOK, 1, flag);
}